// Round 8
// baseline (574.218 us; speedup 1.0000x reference)
//
#include <hip/hip_runtime.h>
#include <stdint.h>

#define NEG_SLOPE 0.2f
#define BN_EPS 1e-5f
#define LOG2E 1.4426950408889634f

typedef unsigned short u16;
typedef unsigned int   u32;
typedef __attribute__((ext_vector_type(2))) float  v2f;
typedef __attribute__((ext_vector_type(4))) float  f32x4;
typedef __attribute__((ext_vector_type(8))) short  short8;

__device__ __forceinline__ float bf2f(u16 u){ return __uint_as_float(((u32)u) << 16); }
__device__ __forceinline__ u16 f2bf(float f){           // round-to-nearest-even
  u32 u = __float_as_uint(f);
  return (u16)((u + 0x7fffu + ((u >> 16) & 1u)) >> 16);
}

// ---------------- build phase ----------------
// y=0: zero counts; y=1..3: fill ell_src[L] with 0xFFFF
__global__ __launch_bounds__(256) void init_k(int* __restrict__ counts, u16* __restrict__ s0,
                                              u16* __restrict__ s1, u16* __restrict__ s2,
                                              int nc, int n0, int n1, int n2){
  int t = blockIdx.x*256 + threadIdx.x;
  int y = blockIdx.y;
  if (y==0){ if (t<nc) counts[t]=0; }
  else {
    u16* sd = (y==1)?s0:(y==2)?s1:s2;
    int n   = (y==1)?n0:(y==2)?n1:n2;
    if (t<n) sd[t]=0xFFFFu;
  }
}

__global__ __launch_bounds__(256) void hist_all_k(const int* __restrict__ el0, const int* __restrict__ el1,
                                                  const int* __restrict__ el2, int* __restrict__ c0,
                                                  int* __restrict__ c1, int* __restrict__ c2,
                                                  int n0, int n1, int n2){
  int t = blockIdx.x*256 + threadIdx.x;
  int L = blockIdx.y;
  const int* dst = (L==0)?(el0+n0):(L==1)?(el1+n1):(el2+n2);
  int* counts    = (L==0)?c0:(L==1)?c1:c2;
  int n          = (L==0)?n0:(L==1)?n1:n2;
  if (t < n) atomicAdd(&counts[dst[t]], 1);
}

// padded scan per layer: row len = (deg+4)&~3 (>= deg+1), self at slot 0
__global__ __launch_bounds__(1024) void scan_all_k(int* __restrict__ c0, int* __restrict__ c1, int* __restrict__ c2,
                         int* __restrict__ ip0, int* __restrict__ ip1, int* __restrict__ ip2,
                         int* __restrict__ cu0, int* __restrict__ cu1, int* __restrict__ cu2,
                         u16* __restrict__ sd0, u16* __restrict__ sd1, u16* __restrict__ sd2,
                         int n0, int n1, int n2){
  int L = blockIdx.x;
  const int* counts = (L==0)?c0:(L==1)?c1:c2;
  int* indptr2      = (L==0)?ip0:(L==1)?ip1:ip2;
  int* cursor       = (L==0)?cu0:(L==1)?cu1:cu2;
  u16* ell_src      = (L==0)?sd0:(L==1)?sd1:sd2;
  int n             = (L==0)?n0:(L==1)?n1:n2;
  __shared__ int part[1024];
  int tid = threadIdx.x;
  int base = tid*4;
  int v0=0,v1=0,v2=0,v3=0;
  if (base+0<n) v0 = (counts[base+0]+4)&~3;
  if (base+1<n) v1 = (counts[base+1]+4)&~3;
  if (base+2<n) v2 = (counts[base+2]+4)&~3;
  if (base+3<n) v3 = (counts[base+3]+4)&~3;
  part[tid] = v0+v1+v2+v3;
  __syncthreads();
  for (int off=1; off<1024; off<<=1){
    int t2 = (tid>=off)?part[tid-off]:0;
    __syncthreads();
    part[tid] += t2;
    __syncthreads();
  }
  int run = (tid>0)?part[tid-1]:0;
  if (base+0<n){ indptr2[base+0]=run; cursor[base+0]=run+1; ell_src[run]=(u16)(base+0); run+=v0; }
  if (base+1<n){ indptr2[base+1]=run; cursor[base+1]=run+1; ell_src[run]=(u16)(base+1); run+=v1; }
  if (base+2<n){ indptr2[base+2]=run; cursor[base+2]=run+1; ell_src[run]=(u16)(base+2); run+=v2; }
  if (base+3<n){ indptr2[base+3]=run; cursor[base+3]=run+1; ell_src[run]=(u16)(base+3); run+=v3; }
  if (tid==0) indptr2[n] = part[1023];
}

__global__ __launch_bounds__(256) void scatter_all_k(const int* __restrict__ el0, const int* __restrict__ el1,
                         const int* __restrict__ el2, int* __restrict__ cu0, int* __restrict__ cu1,
                         int* __restrict__ cu2, u16* __restrict__ sd0, u16* __restrict__ sd1,
                         u16* __restrict__ sd2, int n0, int n1, int n2){
  int t = blockIdx.x*256 + threadIdx.x;
  int L = blockIdx.y;
  const int* el = (L==0)?el0:(L==1)?el1:el2;
  int* cursor   = (L==0)?cu0:(L==1)?cu1:cu2;
  u16* ell_src  = (L==0)?sd0:(L==1)?sd1:sd2;
  int n         = (L==0)?n0:(L==1)?n1:n2;
  if (t < n){
    int dd = el[n + t];
    int p = atomicAdd(&cursor[dd], 1);
    ell_src[p] = (u16)el[t];
  }
}

// counting sort of pool-pairs by max(deg) -> perm (shared by all graphs)
__global__ __launch_bounds__(1024) void pairsort_k(const int* __restrict__ c0, const int* __restrict__ c1,
                         const int* __restrict__ c2, u16* __restrict__ pm0, u16* __restrict__ pm1,
                         u16* __restrict__ pm2, int np0, int np1, int np2){
  int L = blockIdx.x;
  const int* counts = (L==0)?c0:(L==1)?c1:c2;
  u16* perm = (L==0)?pm0:(L==1)?pm1:pm2;
  int np    = (L==0)?np0:(L==1)?np1:np2;
  __shared__ int hist[64];
  __shared__ int pos[64];
  int t = threadIdx.x;
  if (t < 64) hist[t] = 0;
  __syncthreads();
  for (int p=t; p<np; p+=1024){
    int k = min(max(counts[2*p], counts[2*p+1]), 63);
    atomicAdd(&hist[k], 1);
  }
  __syncthreads();
  if (t == 0){ int run=0; for (int i=0;i<64;i++){ pos[i]=run; run+=hist[i]; } }
  __syncthreads();
  for (int p=t; p<np; p+=1024){
    int k = min(max(counts[2*p], counts[2*p+1]), 63);
    int q = atomicAdd(&pos[k], 1);
    perm[q] = (u16)p;
  }
}

// ---------------- layer-0 GEMM: x[n,3] @ W0[3,64] -> h bf16, separable weight factors ----------------
// alsq[r] = (exp2(LOG2E*als), exp2(0.2*LOG2E*als)); aldq same for ald.
// Edge weight later: w = exp(max(t,0.2t)) = max(es*ed, fs*fd)  [exp monotone + separable]
__global__ __launch_bounds__(256) void gemm3_k(const float* __restrict__ x, const float* __restrict__ Wg,
                        const float* __restrict__ asrc, const float* __restrict__ adst,
                        u16* __restrict__ h, float2* __restrict__ alsq, float2* __restrict__ aldq, int nrows8)
{
  const int l = threadIdx.x & 63;
  const int g = l >> 3;
  const int o = l & 7;
  float W0[8], W1[8], W2[8];
  float vs0=0.f,vs1=0.f,vs2=0.f,vd0=0.f,vd1=0.f,vd2=0.f;
  #pragma unroll
  for (int j=0;j<8;j++){
    W0[j] = Wg[      o*8 + j];
    W1[j] = Wg[ 64 + o*8 + j];
    W2[j] = Wg[128 + o*8 + j];
    float as = asrc[o*8 + j], ad = adst[o*8 + j];
    vs0 = fmaf(W0[j], as, vs0); vs1 = fmaf(W1[j], as, vs1); vs2 = fmaf(W2[j], as, vs2);
    vd0 = fmaf(W0[j], ad, vd0); vd1 = fmaf(W1[j], ad, vd1); vd2 = fmaf(W2[j], ad, vd2);
  }
  #pragma unroll
  for (int off=1; off<8; off<<=1){
    vs0 += __shfl_xor(vs0,off); vs1 += __shfl_xor(vs1,off); vs2 += __shfl_xor(vs2,off);
    vd0 += __shfl_xor(vd0,off); vd1 += __shfl_xor(vd1,off); vd2 += __shfl_xor(vd2,off);
  }
  int wv = blockIdx.x*4 + (int)(threadIdx.x>>6);
  int stride = gridDim.x*4;
  for (int blk = wv; blk < nrows8; blk += stride){
    int r = blk*8 + g;
    float x0 = x[(size_t)r*3+0];
    float x1 = x[(size_t)r*3+1];
    float x2 = x[(size_t)r*3+2];
    u32 pk[4];
    #pragma unroll
    for (int j=0;j<8;j+=2){
      float a0 = fmaf(x0, W0[j],   fmaf(x1, W1[j],   x2*W2[j]));
      float a1 = fmaf(x0, W0[j+1], fmaf(x1, W1[j+1], x2*W2[j+1]));
      pk[j>>1] = (u32)f2bf(a0) | ((u32)f2bf(a1) << 16);
    }
    ((int4*)(h + ((size_t)r << 6)))[o] = make_int4((int)pk[0],(int)pk[1],(int)pk[2],(int)pk[3]);
    if (o == 0){
      float va = fmaf(x2, vs2, fmaf(x1, vs1, x0*vs0));
      float vb = fmaf(x2, vd2, fmaf(x1, vd1, x0*vd0));
      alsq[r] = make_float2(exp2f(LOG2E*va), exp2f(NEG_SLOPE*LOG2E*va));
      aldq[r] = make_float2(exp2f(LOG2E*vb), exp2f(NEG_SLOPE*LOG2E*vb));
    }
  }
}

// ---------------- prep (layers 1/2): BN finish of prev layer + W' frags + als/ald B-tile ----------------
__global__ __launch_bounds__(128) void prep_w_k(const float* __restrict__ W, const float* __restrict__ asrc,
                        const float* __restrict__ adst, const float* __restrict__ scratch, float invN,
                        u16* __restrict__ wswz, float* __restrict__ cvec){
  __shared__ float mean_s[64], rstd_s[64], vs_s[64], vd_s[64], cv_s[64], acc[128];
  int t = threadIdx.x;
  float s = 0.f;
  #pragma unroll 8
  for (int b2=0;b2<256;b2++) s += scratch[b2*128 + t];
  acc[t] = s;
  __syncthreads();
  if (t < 64){
    float m = acc[t]*invN;
    float var = acc[64+t]*invN - m*m;
    mean_s[t] = m; rstd_s[t] = rsqrtf(var + BN_EPS);
  }
  __syncthreads();
  if (t < 64){
    float c = 0.f;
    for (int k=0;k<64;k++) c = fmaf(mean_s[k]*rstd_s[k], W[k*64+t], c);
    cv_s[t] = c; cvec[t] = c;
    float vs = 0.f, vd = 0.f;
    for (int col=0; col<64; col++){
      float wv = W[t*64+col];
      vs = fmaf(wv, asrc[col], vs);
      vd = fmaf(wv, adst[col], vd);
    }
    vs_s[t] = rstd_s[t]*vs; vd_s[t] = rstd_s[t]*vd;
  }
  __syncthreads();
  if (t == 0){
    float cs=0.f, cd=0.f;
    for (int col=0; col<64; col++){ cs = fmaf(cv_s[col], asrc[col], cs); cd = fmaf(cv_s[col], adst[col], cd); }
    cvec[64] = cs; cvec[65] = cd;
  }
  if (t < 64){
    #pragma unroll
    for (int f=0; f<8; f++){
      int tt = f >> 1, ch = f & 1;
      #pragma unroll
      for (int j=0; j<8; j++){
        int k   = ch*32 + (t>>4)*8 + j;
        int col = tt*16 + (t&15);
        wswz[(f*64 + t)*8 + j] = f2bf(rstd_s[k] * W[k*64 + col]);
      }
    }
    #pragma unroll
    for (int f=8; f<10; f++){
      int ch = f - 8;
      #pragma unroll
      for (int j=0; j<8; j++){
        int k = ch*32 + (t>>4)*8 + j;
        int colp = t & 15;
        float val = (colp==0)? vs_s[k] : (colp==1)? vd_s[k] : 0.f;
        wswz[(f*64 + t)*8 + j] = f2bf(val);
      }
    }
  }
}

// ---------------- layers 1/2 GEMM via MFMA: h = P @ W' - c; weight factors via augmented B-tile ----------------
__global__ __launch_bounds__(256) void gemm64_mfma_k(const u16* __restrict__ Pin, const u16* __restrict__ wswz,
                        const float* __restrict__ cvec,
                        u16* __restrict__ h, float2* __restrict__ alsq, float2* __restrict__ aldq, int nblk16)
{
  const int l = threadIdx.x & 63;
  const int q = l >> 4;
  const int c = l & 15;
  short8 B[10];
  const int4* wsw = (const int4*)wswz;
  #pragma unroll
  for (int f=0; f<10; f++){
    int4 v = wsw[f*64 + l];
    B[f] = *(short8*)&v;
  }
  float cl[4];
  #pragma unroll
  for (int t=0;t<4;t++) cl[t] = cvec[t*16+c];
  const float const_s = cvec[64], const_d = cvec[65];
  int gw = blockIdx.x*4 + (int)(threadIdx.x>>6);
  int stride = gridDim.x*4;
  for (int blk = gw; blk < nblk16; blk += stride){
    size_t rowbase = (size_t)blk*16;
    const int4* arow = (const int4*)(Pin + (rowbase + c)*64);
    int4 a0v = arow[q];
    int4 a1v = arow[4+q];
    short8 A0 = *(short8*)&a0v, A1 = *(short8*)&a1v;
    f32x4 C0={0.f,0.f,0.f,0.f}, C1=C0, C2=C0, C3=C0, C4=C0;
    C0 = __builtin_amdgcn_mfma_f32_16x16x32_bf16(A0, B[0], C0, 0,0,0);
    C0 = __builtin_amdgcn_mfma_f32_16x16x32_bf16(A1, B[1], C0, 0,0,0);
    C1 = __builtin_amdgcn_mfma_f32_16x16x32_bf16(A0, B[2], C1, 0,0,0);
    C1 = __builtin_amdgcn_mfma_f32_16x16x32_bf16(A1, B[3], C1, 0,0,0);
    C2 = __builtin_amdgcn_mfma_f32_16x16x32_bf16(A0, B[4], C2, 0,0,0);
    C2 = __builtin_amdgcn_mfma_f32_16x16x32_bf16(A1, B[5], C2, 0,0,0);
    C3 = __builtin_amdgcn_mfma_f32_16x16x32_bf16(A0, B[6], C3, 0,0,0);
    C3 = __builtin_amdgcn_mfma_f32_16x16x32_bf16(A1, B[7], C3, 0,0,0);
    C4 = __builtin_amdgcn_mfma_f32_16x16x32_bf16(A0, B[8], C4, 0,0,0);
    C4 = __builtin_amdgcn_mfma_f32_16x16x32_bf16(A1, B[9], C4, 0,0,0);
    #pragma unroll
    for (int t=0;t<4;t++){
      f32x4 C = (t==0)?C0:(t==1)?C1:(t==2)?C2:C3;
      #pragma unroll
      for (int reg=0;reg<4;reg++){
        h[(rowbase + q*4 + reg)*64 + t*16 + c] = f2bf(C[reg] - cl[t]);
      }
    }
    if (c == 0){
      #pragma unroll
      for (int reg=0;reg<4;reg++){
        float v = C4[reg] - const_s;
        alsq[rowbase + q*4 + reg] = make_float2(exp2f(LOG2E*v), exp2f(NEG_SLOPE*LOG2E*v));
      }
    } else if (c == 1){
      #pragma unroll
      for (int reg=0;reg<4;reg++){
        float v = C4[reg] - const_d;
        aldq[rowbase + q*4 + reg] = make_float2(exp2f(LOG2E*v), exp2f(NEG_SLOPE*LOG2E*v));
      }
    }
  }
}

// ---------------- GAT gather + separable-weight softmax + bias + relu + pairwise max-pool ----------------
// wave = 8 groups x 8 lanes; group g owns node 2*perm[pairslot]+(g&1).
// 3-deep software pipeline: meta 3 ahead, h+alq issued 2 iters before consumption.
// Weight per edge: w = max(es*ed_d, fs*fd_d)  -- no transcendental, no mask (loop runs exact cnt).
__global__ __launch_bounds__(256) void gat_pool_k(const u16* __restrict__ h, const float* __restrict__ bias,
                      const int* __restrict__ indptr2, const int* __restrict__ counts,
                      const u16* __restrict__ perm, const u16* __restrict__ ell_src,
                      const float2* __restrict__ alsq, const float2* __restrict__ aldq,
                      u16* __restrict__ P, int log2NS, int nwaves)
{
  const int l = threadIdx.x & 63;
  const int g = l >> 3;
  const int o = l & 7;
  const int NB  = gridDim.x;
  const int bid = blockIdx.x;
  const int lb  = (bid & 7) * (NB >> 3) + (bid >> 3);   // XCD swizzle
  const int wv  = lb * 4 + (int)(threadIdx.x >> 6);
  if (wv >= nwaves) return;
  const int wvu = __builtin_amdgcn_readfirstlane(wv);   // wave-uniform -> SGPR-based addressing

  const int wbits = log2NS - 3;
  const int b    = wvu >> wbits;
  const int widx = wvu & ((1 << wbits) - 1);
  const int pairslot = widx*4 + (g >> 1);
  const int prow = perm[pairslot];
  const int d = 2*prow + (g & 1);
  const int nmask = (1 << log2NS) - 1;
  const int base = b << log2NS;

  const char* __restrict__ hbase  = (const char*)(h + ((size_t)base << 6));   // uniform
  const char* __restrict__ alqb   = (const char*)(alsq + base);               // uniform
  const char* __restrict__ elb    = (const char*)ell_src;                     // uniform
  const u32 olane16 = (u32)o << 4;

  const int p0  = indptr2[d];
  const int cnt = counts[d] + 1;
  const float2 adq = aldq[base + d];
  const float ed_d = adq.x, fd_d = adq.y;
  const u32 moff = (u32)p0 << 1;

  v2f a01={0.f,0.f}, a23={0.f,0.f}, a45={0.f,0.f}, a67={0.f,0.f};
  float z = 0.f;

  // prologue: meta for items 0,1,2; h+alq for items 0,1
  int m0 = *(const u16*)(elb + moff);
  int m1 = *(const u16*)(elb + moff + 2);
  int m2 = *(const u16*)(elb + moff + 4);
  u32 s0 = (u32)(m0 & nmask);
  int4 H0 = *(const int4*)(hbase + ((s0 << 7) + olane16));
  float2 al0 = *(const float2*)(alqb + (s0 << 3));
  u32 s1 = (u32)(m1 & nmask);
  int4 H1 = *(const int4*)(hbase + ((s1 << 7) + olane16));
  float2 al1 = *(const float2*)(alqb + (s1 << 3));

  #pragma unroll 4
  for (int it = 0; it < cnt; ++it){
    // issue h+alq for item it+2 (meta m2)
    u32 s2 = (u32)(m2 & nmask);
    int4 Hn = *(const int4*)(hbase + ((s2 << 7) + olane16));
    float2 al2 = *(const float2*)(alqb + (s2 << 3));
    // meta for item it+3
    int m3 = *(const u16*)(elb + (moff + ((u32)(it + 3) << 1)));
    // consume item it: w = max(es*ed, fs*fd) == exp(lrelu(als+ald))
    float w = fmaxf(al0.x * ed_d, al0.y * fd_d);
    z += w;
    v2f w2 = {w, w};
    a01 += (v2f){ __uint_as_float(((u32)H0.x) << 16), __uint_as_float(((u32)H0.x) & 0xffff0000u) } * w2;
    a23 += (v2f){ __uint_as_float(((u32)H0.y) << 16), __uint_as_float(((u32)H0.y) & 0xffff0000u) } * w2;
    a45 += (v2f){ __uint_as_float(((u32)H0.z) << 16), __uint_as_float(((u32)H0.z) & 0xffff0000u) } * w2;
    a67 += (v2f){ __uint_as_float(((u32)H0.w) << 16), __uint_as_float(((u32)H0.w) & 0xffff0000u) } * w2;
    // shift pipeline (erased by unroll + copy-prop)
    m0 = m1; m1 = m2; m2 = m3;
    H0 = H1; al0 = al1;
    H1 = Hn; al1 = al2;
  }

  float rz = __builtin_amdgcn_rcpf(z);
  const float* bp = bias + (o << 3);          // loaded after the loop: not live across it
  float4 bA = *(const float4*)(bp);
  float4 bB = *(const float4*)(bp + 4);
  float q0 = fmaxf(fmaf(a01.x, rz, bA.x), 0.f);
  float q1 = fmaxf(fmaf(a01.y, rz, bA.y), 0.f);
  float q2 = fmaxf(fmaf(a23.x, rz, bA.z), 0.f);
  float q3 = fmaxf(fmaf(a23.y, rz, bA.w), 0.f);
  float q4 = fmaxf(fmaf(a45.x, rz, bB.x), 0.f);
  float q5 = fmaxf(fmaf(a45.y, rz, bB.y), 0.f);
  float q6 = fmaxf(fmaf(a67.x, rz, bB.z), 0.f);
  float q7 = fmaxf(fmaf(a67.y, rz, bB.w), 0.f);
  q0 = fmaxf(q0, __shfl_xor(q0, 8));
  q1 = fmaxf(q1, __shfl_xor(q1, 8));
  q2 = fmaxf(q2, __shfl_xor(q2, 8));
  q3 = fmaxf(q3, __shfl_xor(q3, 8));
  q4 = fmaxf(q4, __shfl_xor(q4, 8));
  q5 = fmaxf(q5, __shfl_xor(q5, 8));
  q6 = fmaxf(q6, __shfl_xor(q6, 8));
  q7 = fmaxf(q7, __shfl_xor(q7, 8));
  if ((g & 1) == 0){
    u32 w0 = (u32)f2bf(q0) | ((u32)f2bf(q1) << 16);
    u32 w1 = (u32)f2bf(q2) | ((u32)f2bf(q3) << 16);
    u32 w2p = (u32)f2bf(q4) | ((u32)f2bf(q5) << 16);
    u32 w3 = (u32)f2bf(q6) | ((u32)f2bf(q7) << 16);
    char* Pb = (char*)P + (((size_t)b << (log2NS - 1)) << 7);   // uniform base
    *(int4*)(Pb + (((u32)prow << 7) + olane16)) = make_int4((int)w0,(int)w1,(int)w2p,(int)w3);
  }
}

// ---------------- BatchNorm stats (stage 1) ----------------
__global__ __launch_bounds__(256) void bn_stats_k(const u16* __restrict__ P, float* __restrict__ scratch, int iters){
  const int l = threadIdx.x & 63;
  int gw = blockIdx.x*4 + (threadIdx.x>>6);
  int GW = gridDim.x*4;
  float s = 0.f, s2 = 0.f;
  #pragma unroll 4
  for (int i = 0; i < iters; i++){
    int r = gw + i*GW;
    float v = bf2f(P[(size_t)r*64 + l]);
    s += v; s2 = fmaf(v, v, s2);
  }
  __shared__ float ls[256], ls2[256];
  ls[threadIdx.x] = s; ls2[threadIdx.x] = s2;
  __syncthreads();
  if (threadIdx.x < 64){
    float S  = ls[threadIdx.x] + ls[threadIdx.x+64] + ls[threadIdx.x+128] + ls[threadIdx.x+192];
    float S2 = ls2[threadIdx.x] + ls2[threadIdx.x+64] + ls2[threadIdx.x+128] + ls2[threadIdx.x+192];
    scratch[blockIdx.x*128 + threadIdx.x] = S;
    scratch[blockIdx.x*128 + 64 + threadIdx.x] = S2;
  }
}

__global__ __launch_bounds__(128) void bn_finish_k(const float* __restrict__ scratch, float* __restrict__ stats,
                                                   int nblocks, float invN){
  __shared__ float accs[128];
  int j = threadIdx.x;
  float s = 0.f;
  #pragma unroll 8
  for (int b=0;b<nblocks;b++) s += scratch[b*128 + j];
  accs[j] = s;
  __syncthreads();
  if (j < 64){
    float m = accs[j]*invN;
    float var = accs[j+64]*invN - m*m;
    stats[j] = m;
    stats[64+j] = rsqrtf(var + BN_EPS);
  }
}

// ---------------- final BN apply: bf16 P -> f32 out ----------------
__global__ __launch_bounds__(256) void bn_apply_k(const u32* __restrict__ P2, const float* __restrict__ stats,
                                                  float4* __restrict__ out, int nq){
  int t = blockIdx.x*256 + threadIdx.x;
  if (t >= nq) return;
  int l = (t*4) & 63;
  u32 v0 = P2[t*2], v1 = P2[t*2+1];
  float4 r;
  r.x = (__uint_as_float((v0 & 0xffffu) << 16) - stats[l+0]) * stats[64+l+0];
  r.y = (__uint_as_float( v0 & 0xffff0000u    ) - stats[l+1]) * stats[64+l+1];
  r.z = (__uint_as_float((v1 & 0xffffu) << 16) - stats[l+2]) * stats[64+l+2];
  r.w = (__uint_as_float( v1 & 0xffff0000u    ) - stats[l+3]) * stats[64+l+3];
  out[t] = r;
}

// ---------------- launcher ----------------
extern "C" void kernel_launch(void* const* d_in, const int* in_sizes, int n_in,
                              void* d_out, int out_size, void* d_ws, size_t ws_size,
                              hipStream_t stream)
{
  const float* x      = (const float*)d_in[0];
  const float* Wl[3]  = {(const float*)d_in[1], (const float*)d_in[7],  (const float*)d_in[13]};
  const float* asl[3] = {(const float*)d_in[2], (const float*)d_in[8],  (const float*)d_in[14]};
  const float* adl[3] = {(const float*)d_in[3], (const float*)d_in[9],  (const float*)d_in[15]};
  const float* bl[3]  = {(const float*)d_in[4], (const float*)d_in[10], (const float*)d_in[16]};
  const int*   el[3]  = {(const int*)d_in[5],   (const int*)d_in[11],   (const int*)d_in[17]};

  const int NS[4]  = {4096, 2048, 1024, 512};
  const int EPB[3] = {32768, 16384, 8192};
  const int LOG2NS[3] = {12, 11, 10};
  const int ECAP[3] = {32768+4*4096, 16384+4*2048, 8192+4*1024};  // 49152, 24576, 12288
  const int BATCH = 256;

  char* ws = (char*)d_ws;
  size_t off = 0;
  auto alloc = [&](size_t bytes)->char*{
    char* p = ws + off; off += (bytes + 255) & ~(size_t)255; return p;
  };

  u16*    hbuf    = (u16*)alloc((size_t)BATCH*NS[0]*64*2);            // 128 MB
  u16*    Pbuf    = (u16*)alloc((size_t)BATCH*NS[1]*64*2);            //  64 MB
  float2* alsq    = (float2*)alloc((size_t)BATCH*NS[0]*8);            //   8 MB (es, fs)
  float2* aldq    = (float2*)alloc((size_t)BATCH*NS[0]*8);            //   8 MB (ed, fd)
  float*  scratch = (float*)alloc(256*128*4);
  float*  stats   = (float*)alloc(128*4);
  u16*    wswz    = (u16*)alloc(10*64*8*2);
  float*  cvec    = (float*)alloc(128*4);
  int* counts_all = (int*)alloc((size_t)(NS[0]+NS[1]+NS[2])*4);
  int* cursor_all = (int*)alloc((size_t)(NS[0]+NS[1]+NS[2])*4);
  int *counts[3], *cursor[3], *indptr2[3];
  u16* ell_src[3];
  u16* perm[3];
  counts[0]=counts_all; counts[1]=counts_all+NS[0]; counts[2]=counts_all+NS[0]+NS[1];
  cursor[0]=cursor_all; cursor[1]=cursor_all+NS[0]; cursor[2]=cursor_all+NS[0]+NS[1];
  for (int i=0;i<3;i++){
    indptr2[i] = (int*)alloc((size_t)(NS[i]+1)*4);
    ell_src[i] = (u16*)alloc((size_t)(ECAP[i]+16)*2);
    perm[i]    = (u16*)alloc((size_t)NS[i]);      // NS/2 pairs * 2B
  }
  if (off > ws_size) return;

  // ---- build ----
  int ctot = NS[0]+NS[1]+NS[2];
  {
    dim3 ginit((ECAP[0]+16+255)/256, 4);
    init_k<<<ginit, 256, 0, stream>>>(counts_all, ell_src[0], ell_src[1], ell_src[2],
                                      ctot, ECAP[0]+16, ECAP[1]+16, ECAP[2]+16);
    dim3 ghist(EPB[0]/256, 3);
    hist_all_k<<<ghist, 256, 0, stream>>>(el[0], el[1], el[2], counts[0], counts[1], counts[2],
                                          EPB[0], EPB[1], EPB[2]);
    scan_all_k<<<3, 1024, 0, stream>>>(counts[0], counts[1], counts[2],
                                       indptr2[0], indptr2[1], indptr2[2],
                                       cursor[0], cursor[1], cursor[2],
                                       ell_src[0], ell_src[1], ell_src[2],
                                       NS[0], NS[1], NS[2]);
    scatter_all_k<<<ghist, 256, 0, stream>>>(el[0], el[1], el[2],
                                             cursor[0], cursor[1], cursor[2],
                                             ell_src[0], ell_src[1], ell_src[2],
                                             EPB[0], EPB[1], EPB[2]);
    pairsort_k<<<3, 1024, 0, stream>>>(counts[0], counts[1], counts[2],
                                       perm[0], perm[1], perm[2],
                                       NS[0]/2, NS[1]/2, NS[2]/2);
  }

  // ---- layers ----
  for (int i=0;i<3;i++){
    int ntot = BATCH*NS[i];

    if (i==0){
      gemm3_k<<<1024, 256, 0, stream>>>(x, Wl[0], asl[0], adl[0], hbuf, alsq, aldq, ntot/8);
    } else {
      float invN = 1.0f / (float)(BATCH*NS[i]);   // prev pooled rows = BATCH*NS[i-1]/2 = BATCH*NS[i]
      prep_w_k<<<1, 128, 0, stream>>>(Wl[i], asl[i], adl[i], scratch, invN, wswz, cvec);
      gemm64_mfma_k<<<2048, 256, 0, stream>>>(Pbuf, wswz, cvec, hbuf, alsq, aldq, ntot/16);
    }

    int nwaves = ntot/8;
    gat_pool_k<<<nwaves/4, 256, 0, stream>>>(hbuf, bl[i], indptr2[i], counts[i], perm[i],
                                             ell_src[i], alsq, aldq,
                                             Pbuf, LOG2NS[i], nwaves);

    bn_stats_k<<<256, 256, 0, stream>>>(Pbuf, scratch, (ntot/2)/1024);
  }

  // final BN: finish stats of layer 2, then materialize into d_out
  bn_finish_k<<<1, 128, 0, stream>>>(scratch, stats, 256, 1.0f/(float)(BATCH*NS[3]));
  int nq = out_size/4;
  bn_apply_k<<<(nq+255)/256, 256, 0, stream>>>((const u32*)Pbuf, stats, (float4*)d_out, nq);
}

// Round 11
// 572.593 us; speedup vs baseline: 1.0028x; 1.0028x over previous
//
#include <hip/hip_runtime.h>
#include <stdint.h>

#define NEG_SLOPE 0.2f
#define BN_EPS 1e-5f
#define LOG2E 1.4426950408889634f

typedef unsigned short u16;
typedef unsigned int   u32;
typedef __attribute__((ext_vector_type(2))) float  v2f;
typedef __attribute__((ext_vector_type(4))) float  f32x4;
typedef __attribute__((ext_vector_type(8))) short  short8;

__device__ __forceinline__ float bf2f(u16 u){ return __uint_as_float(((u32)u) << 16); }
__device__ __forceinline__ u16 f2bf(float f){           // round-to-nearest-even
  u32 u = __float_as_uint(f);
  return (u16)((u + 0x7fffu + ((u >> 16) & 1u)) >> 16);
}

// ---------------- build phase ----------------
// y=0: zero counts; y=1..3: fill ell_src[L] with 0xFFFF
__global__ __launch_bounds__(256) void init_k(int* __restrict__ counts, u16* __restrict__ s0,
                                              u16* __restrict__ s1, u16* __restrict__ s2,
                                              int nc, int n0, int n1, int n2){
  int t = blockIdx.x*256 + threadIdx.x;
  int y = blockIdx.y;
  if (y==0){ if (t<nc) counts[t]=0; }
  else {
    u16* sd = (y==1)?s0:(y==2)?s1:s2;
    int n   = (y==1)?n0:(y==2)?n1:n2;
    if (t<n) sd[t]=0xFFFFu;
  }
}

__global__ __launch_bounds__(256) void hist_all_k(const int* __restrict__ el0, const int* __restrict__ el1,
                                                  const int* __restrict__ el2, int* __restrict__ c0,
                                                  int* __restrict__ c1, int* __restrict__ c2,
                                                  int n0, int n1, int n2){
  int t = blockIdx.x*256 + threadIdx.x;
  int L = blockIdx.y;
  const int* dst = (L==0)?(el0+n0):(L==1)?(el1+n1):(el2+n2);
  int* counts    = (L==0)?c0:(L==1)?c1:c2;
  int n          = (L==0)?n0:(L==1)?n1:n2;
  if (t < n) atomicAdd(&counts[dst[t]], 1);
}

// padded scan per layer: row len = (deg+4)&~3 (>= deg+1), self at slot 0
__global__ __launch_bounds__(1024) void scan_all_k(int* __restrict__ c0, int* __restrict__ c1, int* __restrict__ c2,
                         int* __restrict__ ip0, int* __restrict__ ip1, int* __restrict__ ip2,
                         int* __restrict__ cu0, int* __restrict__ cu1, int* __restrict__ cu2,
                         u16* __restrict__ sd0, u16* __restrict__ sd1, u16* __restrict__ sd2,
                         int n0, int n1, int n2){
  int L = blockIdx.x;
  const int* counts = (L==0)?c0:(L==1)?c1:c2;
  int* indptr2      = (L==0)?ip0:(L==1)?ip1:ip2;
  int* cursor       = (L==0)?cu0:(L==1)?cu1:cu2;
  u16* ell_src      = (L==0)?sd0:(L==1)?sd1:sd2;
  int n             = (L==0)?n0:(L==1)?n1:n2;
  __shared__ int part[1024];
  int tid = threadIdx.x;
  int base = tid*4;
  int v0=0,v1=0,v2=0,v3=0;
  if (base+0<n) v0 = (counts[base+0]+4)&~3;
  if (base+1<n) v1 = (counts[base+1]+4)&~3;
  if (base+2<n) v2 = (counts[base+2]+4)&~3;
  if (base+3<n) v3 = (counts[base+3]+4)&~3;
  part[tid] = v0+v1+v2+v3;
  __syncthreads();
  for (int off=1; off<1024; off<<=1){
    int t2 = (tid>=off)?part[tid-off]:0;
    __syncthreads();
    part[tid] += t2;
    __syncthreads();
  }
  int run = (tid>0)?part[tid-1]:0;
  if (base+0<n){ indptr2[base+0]=run; cursor[base+0]=run+1; ell_src[run]=(u16)(base+0); run+=v0; }
  if (base+1<n){ indptr2[base+1]=run; cursor[base+1]=run+1; ell_src[run]=(u16)(base+1); run+=v1; }
  if (base+2<n){ indptr2[base+2]=run; cursor[base+2]=run+1; ell_src[run]=(u16)(base+2); run+=v2; }
  if (base+3<n){ indptr2[base+3]=run; cursor[base+3]=run+1; ell_src[run]=(u16)(base+3); run+=v3; }
  if (tid==0) indptr2[n] = part[1023];
}

__global__ __launch_bounds__(256) void scatter_all_k(const int* __restrict__ el0, const int* __restrict__ el1,
                         const int* __restrict__ el2, int* __restrict__ cu0, int* __restrict__ cu1,
                         int* __restrict__ cu2, u16* __restrict__ sd0, u16* __restrict__ sd1,
                         u16* __restrict__ sd2, int n0, int n1, int n2){
  int t = blockIdx.x*256 + threadIdx.x;
  int L = blockIdx.y;
  const int* el = (L==0)?el0:(L==1)?el1:el2;
  int* cursor   = (L==0)?cu0:(L==1)?cu1:cu2;
  u16* ell_src  = (L==0)?sd0:(L==1)?sd1:sd2;
  int n         = (L==0)?n0:(L==1)?n1:n2;
  if (t < n){
    int dd = el[n + t];
    int p = atomicAdd(&cursor[dd], 1);
    ell_src[p] = (u16)el[t];
  }
}

// counting sort of pool-pairs by max(deg) -> perm (shared by all graphs)
__global__ __launch_bounds__(1024) void pairsort_k(const int* __restrict__ c0, const int* __restrict__ c1,
                         const int* __restrict__ c2, u16* __restrict__ pm0, u16* __restrict__ pm1,
                         u16* __restrict__ pm2, int np0, int np1, int np2){
  int L = blockIdx.x;
  const int* counts = (L==0)?c0:(L==1)?c1:c2;
  u16* perm = (L==0)?pm0:(L==1)?pm1:pm2;
  int np    = (L==0)?np0:(L==1)?np1:np2;
  __shared__ int hist[64];
  __shared__ int pos[64];
  int t = threadIdx.x;
  if (t < 64) hist[t] = 0;
  __syncthreads();
  for (int p=t; p<np; p+=1024){
    int k = min(max(counts[2*p], counts[2*p+1]), 63);
    atomicAdd(&hist[k], 1);
  }
  __syncthreads();
  if (t == 0){ int run=0; for (int i=0;i<64;i++){ pos[i]=run; run+=hist[i]; } }
  __syncthreads();
  for (int p=t; p<np; p+=1024){
    int k = min(max(counts[2*p], counts[2*p+1]), 63);
    int q = atomicAdd(&pos[k], 1);
    perm[q] = (u16)p;
  }
}

// ---------------- layer-0 GEMM: x[n,3] @ W0[3,64] -> h bf16, separable weight factors ----------------
// alsq[r] = (exp2(LOG2E*als), exp2(0.2*LOG2E*als)); aldq same for ald.
// Edge weight later: w = exp(max(t,0.2t)) = max(es*ed, fs*fd)  [exp monotone + separable]
__global__ __launch_bounds__(256) void gemm3_k(const float* __restrict__ x, const float* __restrict__ Wg,
                        const float* __restrict__ asrc, const float* __restrict__ adst,
                        u16* __restrict__ h, float2* __restrict__ alsq, float2* __restrict__ aldq, int nrows8)
{
  const int l = threadIdx.x & 63;
  const int g = l >> 3;
  const int o = l & 7;
  float W0[8], W1[8], W2[8];
  float vs0=0.f,vs1=0.f,vs2=0.f,vd0=0.f,vd1=0.f,vd2=0.f;
  #pragma unroll
  for (int j=0;j<8;j++){
    W0[j] = Wg[      o*8 + j];
    W1[j] = Wg[ 64 + o*8 + j];
    W2[j] = Wg[128 + o*8 + j];
    float as = asrc[o*8 + j], ad = adst[o*8 + j];
    vs0 = fmaf(W0[j], as, vs0); vs1 = fmaf(W1[j], as, vs1); vs2 = fmaf(W2[j], as, vs2);
    vd0 = fmaf(W0[j], ad, vd0); vd1 = fmaf(W1[j], ad, vd1); vd2 = fmaf(W2[j], ad, vd2);
  }
  #pragma unroll
  for (int off=1; off<8; off<<=1){
    vs0 += __shfl_xor(vs0,off); vs1 += __shfl_xor(vs1,off); vs2 += __shfl_xor(vs2,off);
    vd0 += __shfl_xor(vd0,off); vd1 += __shfl_xor(vd1,off); vd2 += __shfl_xor(vd2,off);
  }
  int wv = blockIdx.x*4 + (int)(threadIdx.x>>6);
  int stride = gridDim.x*4;
  for (int blk = wv; blk < nrows8; blk += stride){
    int r = blk*8 + g;
    float x0 = x[(size_t)r*3+0];
    float x1 = x[(size_t)r*3+1];
    float x2 = x[(size_t)r*3+2];
    u32 pk[4];
    #pragma unroll
    for (int j=0;j<8;j+=2){
      float a0 = fmaf(x0, W0[j],   fmaf(x1, W1[j],   x2*W2[j]));
      float a1 = fmaf(x0, W0[j+1], fmaf(x1, W1[j+1], x2*W2[j+1]));
      pk[j>>1] = (u32)f2bf(a0) | ((u32)f2bf(a1) << 16);
    }
    ((int4*)(h + ((size_t)r << 6)))[o] = make_int4((int)pk[0],(int)pk[1],(int)pk[2],(int)pk[3]);
    if (o == 0){
      float va = fmaf(x2, vs2, fmaf(x1, vs1, x0*vs0));
      float vb = fmaf(x2, vd2, fmaf(x1, vd1, x0*vd0));
      alsq[r] = make_float2(exp2f(LOG2E*va), exp2f(NEG_SLOPE*LOG2E*va));
      aldq[r] = make_float2(exp2f(LOG2E*vb), exp2f(NEG_SLOPE*LOG2E*vb));
    }
  }
}

// ---------------- prep (layers 1/2): BN finish of prev layer + W' frags + als/ald B-tile ----------------
__global__ __launch_bounds__(128) void prep_w_k(const float* __restrict__ W, const float* __restrict__ asrc,
                        const float* __restrict__ adst, const float* __restrict__ scratch, float invN,
                        u16* __restrict__ wswz, float* __restrict__ cvec){
  __shared__ float mean_s[64], rstd_s[64], vs_s[64], vd_s[64], cv_s[64], acc[128];
  int t = threadIdx.x;
  float s = 0.f;
  #pragma unroll 8
  for (int b2=0;b2<256;b2++) s += scratch[b2*128 + t];
  acc[t] = s;
  __syncthreads();
  if (t < 64){
    float m = acc[t]*invN;
    float var = acc[64+t]*invN - m*m;
    mean_s[t] = m; rstd_s[t] = rsqrtf(var + BN_EPS);
  }
  __syncthreads();
  if (t < 64){
    float c = 0.f;
    for (int k=0;k<64;k++) c = fmaf(mean_s[k]*rstd_s[k], W[k*64+t], c);
    cv_s[t] = c; cvec[t] = c;
    float vs = 0.f, vd = 0.f;
    for (int col=0; col<64; col++){
      float wv = W[t*64+col];
      vs = fmaf(wv, asrc[col], vs);
      vd = fmaf(wv, adst[col], vd);
    }
    vs_s[t] = rstd_s[t]*vs; vd_s[t] = rstd_s[t]*vd;
  }
  __syncthreads();
  if (t == 0){
    float cs=0.f, cd=0.f;
    for (int col=0; col<64; col++){ cs = fmaf(cv_s[col], asrc[col], cs); cd = fmaf(cv_s[col], adst[col], cd); }
    cvec[64] = cs; cvec[65] = cd;
  }
  if (t < 64){
    #pragma unroll
    for (int f=0; f<8; f++){
      int tt = f >> 1, ch = f & 1;
      #pragma unroll
      for (int j=0; j<8; j++){
        int k   = ch*32 + (t>>4)*8 + j;
        int col = tt*16 + (t&15);
        wswz[(f*64 + t)*8 + j] = f2bf(rstd_s[k] * W[k*64 + col]);
      }
    }
    #pragma unroll
    for (int f=8; f<10; f++){
      int ch = f - 8;
      #pragma unroll
      for (int j=0; j<8; j++){
        int k = ch*32 + (t>>4)*8 + j;
        int colp = t & 15;
        float val = (colp==0)? vs_s[k] : (colp==1)? vd_s[k] : 0.f;
        wswz[(f*64 + t)*8 + j] = f2bf(val);
      }
    }
  }
}

// ---------------- layers 1/2 GEMM via MFMA: h = P @ W' - c; weight factors via augmented B-tile ----------------
__global__ __launch_bounds__(256) void gemm64_mfma_k(const u16* __restrict__ Pin, const u16* __restrict__ wswz,
                        const float* __restrict__ cvec,
                        u16* __restrict__ h, float2* __restrict__ alsq, float2* __restrict__ aldq, int nblk16)
{
  const int l = threadIdx.x & 63;
  const int q = l >> 4;
  const int c = l & 15;
  short8 B[10];
  const int4* wsw = (const int4*)wswz;
  #pragma unroll
  for (int f=0; f<10; f++){
    int4 v = wsw[f*64 + l];
    B[f] = *(short8*)&v;
  }
  float cl[4];
  #pragma unroll
  for (int t=0;t<4;t++) cl[t] = cvec[t*16+c];
  const float const_s = cvec[64], const_d = cvec[65];
  int gw = blockIdx.x*4 + (int)(threadIdx.x>>6);
  int stride = gridDim.x*4;
  for (int blk = gw; blk < nblk16; blk += stride){
    size_t rowbase = (size_t)blk*16;
    const int4* arow = (const int4*)(Pin + (rowbase + c)*64);
    int4 a0v = arow[q];
    int4 a1v = arow[4+q];
    short8 A0 = *(short8*)&a0v, A1 = *(short8*)&a1v;
    f32x4 C0={0.f,0.f,0.f,0.f}, C1=C0, C2=C0, C3=C0, C4=C0;
    C0 = __builtin_amdgcn_mfma_f32_16x16x32_bf16(A0, B[0], C0, 0,0,0);
    C0 = __builtin_amdgcn_mfma_f32_16x16x32_bf16(A1, B[1], C0, 0,0,0);
    C1 = __builtin_amdgcn_mfma_f32_16x16x32_bf16(A0, B[2], C1, 0,0,0);
    C1 = __builtin_amdgcn_mfma_f32_16x16x32_bf16(A1, B[3], C1, 0,0,0);
    C2 = __builtin_amdgcn_mfma_f32_16x16x32_bf16(A0, B[4], C2, 0,0,0);
    C2 = __builtin_amdgcn_mfma_f32_16x16x32_bf16(A1, B[5], C2, 0,0,0);
    C3 = __builtin_amdgcn_mfma_f32_16x16x32_bf16(A0, B[6], C3, 0,0,0);
    C3 = __builtin_amdgcn_mfma_f32_16x16x32_bf16(A1, B[7], C3, 0,0,0);
    C4 = __builtin_amdgcn_mfma_f32_16x16x32_bf16(A0, B[8], C4, 0,0,0);
    C4 = __builtin_amdgcn_mfma_f32_16x16x32_bf16(A1, B[9], C4, 0,0,0);
    #pragma unroll
    for (int t=0;t<4;t++){
      f32x4 C = (t==0)?C0:(t==1)?C1:(t==2)?C2:C3;
      #pragma unroll
      for (int reg=0;reg<4;reg++){
        h[(rowbase + q*4 + reg)*64 + t*16 + c] = f2bf(C[reg] - cl[t]);
      }
    }
    if (c == 0){
      #pragma unroll
      for (int reg=0;reg<4;reg++){
        float v = C4[reg] - const_s;
        alsq[rowbase + q*4 + reg] = make_float2(exp2f(LOG2E*v), exp2f(NEG_SLOPE*LOG2E*v));
      }
    } else if (c == 1){
      #pragma unroll
      for (int reg=0;reg<4;reg++){
        float v = C4[reg] - const_d;
        aldq[rowbase + q*4 + reg] = make_float2(exp2f(LOG2E*v), exp2f(NEG_SLOPE*LOG2E*v));
      }
    }
  }
}

// ---------------- GAT gather + separable-weight softmax + bias + relu + pairwise max-pool ----------------
// wave = 8 groups x 8 lanes; group g owns node 2*perm[pairslot]+(g&1).
// 4-deep software pipeline: meta 4 ahead, h+alq issued 3 iters before consumption
// (deepened from 2-ahead: r8 showed VALU-time 88us but stall 60us -- latency-bound).
// Weight per edge: w = max(es*ed_d, fs*fd_d)  -- no transcendental, no mask.
__global__ __launch_bounds__(256) void gat_pool_k(const u16* __restrict__ h, const float* __restrict__ bias,
                      const int* __restrict__ indptr2, const int* __restrict__ counts,
                      const u16* __restrict__ perm, const u16* __restrict__ ell_src,
                      const float2* __restrict__ alsq, const float2* __restrict__ aldq,
                      u16* __restrict__ P, int log2NS, int nwaves)
{
  const int l = threadIdx.x & 63;
  const int g = l >> 3;
  const int o = l & 7;
  const int NB  = gridDim.x;
  const int bid = blockIdx.x;
  const int lb  = (bid & 7) * (NB >> 3) + (bid >> 3);   // XCD swizzle
  const int wv  = lb * 4 + (int)(threadIdx.x >> 6);
  if (wv >= nwaves) return;
  const int wvu = __builtin_amdgcn_readfirstlane(wv);   // wave-uniform -> SGPR-based addressing

  const int wbits = log2NS - 3;
  const int b    = wvu >> wbits;
  const int widx = wvu & ((1 << wbits) - 1);
  const int pairslot = widx*4 + (g >> 1);
  const int prow = perm[pairslot];
  const int d = 2*prow + (g & 1);
  const int nmask = (1 << log2NS) - 1;
  const int base = b << log2NS;

  const char* __restrict__ hbase  = (const char*)(h + ((size_t)base << 6));   // uniform
  const char* __restrict__ alqb   = (const char*)(alsq + base);               // uniform
  const char* __restrict__ elb    = (const char*)ell_src;                     // uniform
  const u32 olane16 = (u32)o << 4;

  const int p0  = indptr2[d];
  const int cnt = counts[d] + 1;
  const float2 adq = aldq[base + d];
  const float ed_d = adq.x, fd_d = adq.y;
  const u32 moff = (u32)p0 << 1;

  v2f a01={0.f,0.f}, a23={0.f,0.f}, a45={0.f,0.f}, a67={0.f,0.f};
  float z = 0.f;

  // prologue: meta for items 0..3; h+alq for items 0..2
  // (max meta index p0+cnt+3 = p0+deg+4, inside the +16-slot pad; prefetch-only
  //  items use garbage meta masked by nmask -- in-bounds reads, never consumed)
  int m0 = *(const u16*)(elb + moff);
  int m1 = *(const u16*)(elb + moff + 2);
  int m2 = *(const u16*)(elb + moff + 4);
  int m3 = *(const u16*)(elb + moff + 6);
  u32 s0 = (u32)(m0 & nmask);
  int4 H0 = *(const int4*)(hbase + ((s0 << 7) + olane16));
  float2 al0 = *(const float2*)(alqb + (s0 << 3));
  u32 s1 = (u32)(m1 & nmask);
  int4 H1 = *(const int4*)(hbase + ((s1 << 7) + olane16));
  float2 al1 = *(const float2*)(alqb + (s1 << 3));
  u32 s2 = (u32)(m2 & nmask);
  int4 H2 = *(const int4*)(hbase + ((s2 << 7) + olane16));
  float2 al2 = *(const float2*)(alqb + (s2 << 3));

  #pragma unroll 4
  for (int it = 0; it < cnt; ++it){
    // issue h+alq for item it+3 (meta m3)
    u32 s3 = (u32)(m3 & nmask);
    int4 H3 = *(const int4*)(hbase + ((s3 << 7) + olane16));
    float2 al3 = *(const float2*)(alqb + (s3 << 3));
    // meta for item it+4
    int m4 = *(const u16*)(elb + (moff + ((u32)(it + 4) << 1)));
    // consume item it: w = max(es*ed, fs*fd) == exp(lrelu(als+ald))
    float w = fmaxf(al0.x * ed_d, al0.y * fd_d);
    z += w;
    v2f w2 = {w, w};
    a01 += (v2f){ __uint_as_float(((u32)H0.x) << 16), __uint_as_float(((u32)H0.x) & 0xffff0000u) } * w2;
    a23 += (v2f){ __uint_as_float(((u32)H0.y) << 16), __uint_as_float(((u32)H0.y) & 0xffff0000u) } * w2;
    a45 += (v2f){ __uint_as_float(((u32)H0.z) << 16), __uint_as_float(((u32)H0.z) & 0xffff0000u) } * w2;
    a67 += (v2f){ __uint_as_float(((u32)H0.w) << 16), __uint_as_float(((u32)H0.w) & 0xffff0000u) } * w2;
    // shift pipeline (erased by unroll + copy-prop)
    m3 = m4;
    H0 = H1; H1 = H2; H2 = H3;
    al0 = al1; al1 = al2; al2 = al3;
  }

  float rz = __builtin_amdgcn_rcpf(z);
  const float* bp = bias + (o << 3);          // loaded after the loop: not live across it
  float4 bA = *(const float4*)(bp);
  float4 bB = *(const float4*)(bp + 4);
  float q0 = fmaxf(fmaf(a01.x, rz, bA.x), 0.f);
  float q1 = fmaxf(fmaf(a01.y, rz, bA.y), 0.f);
  float q2 = fmaxf(fmaf(a23.x, rz, bA.z), 0.f);
  float q3 = fmaxf(fmaf(a23.y, rz, bA.w), 0.f);
  float q4 = fmaxf(fmaf(a45.x, rz, bB.x), 0.f);
  float q5 = fmaxf(fmaf(a45.y, rz, bB.y), 0.f);
  float q6 = fmaxf(fmaf(a67.x, rz, bB.z), 0.f);
  float q7 = fmaxf(fmaf(a67.y, rz, bB.w), 0.f);
  q0 = fmaxf(q0, __shfl_xor(q0, 8));
  q1 = fmaxf(q1, __shfl_xor(q1, 8));
  q2 = fmaxf(q2, __shfl_xor(q2, 8));
  q3 = fmaxf(q3, __shfl_xor(q3, 8));
  q4 = fmaxf(q4, __shfl_xor(q4, 8));
  q5 = fmaxf(q5, __shfl_xor(q5, 8));
  q6 = fmaxf(q6, __shfl_xor(q6, 8));
  q7 = fmaxf(q7, __shfl_xor(q7, 8));
  if ((g & 1) == 0){
    u32 w0 = (u32)f2bf(q0) | ((u32)f2bf(q1) << 16);
    u32 w1 = (u32)f2bf(q2) | ((u32)f2bf(q3) << 16);
    u32 w2p = (u32)f2bf(q4) | ((u32)f2bf(q5) << 16);
    u32 w3 = (u32)f2bf(q6) | ((u32)f2bf(q7) << 16);
    char* Pb = (char*)P + (((size_t)b << (log2NS - 1)) << 7);   // uniform base
    *(int4*)(Pb + (((u32)prow << 7) + olane16)) = make_int4((int)w0,(int)w1,(int)w2p,(int)w3);
  }
}

// ---------------- BatchNorm stats (stage 1) ----------------
__global__ __launch_bounds__(256) void bn_stats_k(const u16* __restrict__ P, float* __restrict__ scratch, int iters){
  const int l = threadIdx.x & 63;
  int gw = blockIdx.x*4 + (threadIdx.x>>6);
  int GW = gridDim.x*4;
  float s = 0.f, s2 = 0.f;
  #pragma unroll 4
  for (int i = 0; i < iters; i++){
    int r = gw + i*GW;
    float v = bf2f(P[(size_t)r*64 + l]);
    s += v; s2 = fmaf(v, v, s2);
  }
  __shared__ float ls[256], ls2[256];
  ls[threadIdx.x] = s; ls2[threadIdx.x] = s2;
  __syncthreads();
  if (threadIdx.x < 64){
    float S  = ls[threadIdx.x] + ls[threadIdx.x+64] + ls[threadIdx.x+128] + ls[threadIdx.x+192];
    float S2 = ls2[threadIdx.x] + ls2[threadIdx.x+64] + ls2[threadIdx.x+128] + ls2[threadIdx.x+192];
    scratch[blockIdx.x*128 + threadIdx.x] = S;
    scratch[blockIdx.x*128 + 64 + threadIdx.x] = S2;
  }
}

__global__ __launch_bounds__(128) void bn_finish_k(const float* __restrict__ scratch, float* __restrict__ stats,
                                                   int nblocks, float invN){
  __shared__ float accs[128];
  int j = threadIdx.x;
  float s = 0.f;
  #pragma unroll 8
  for (int b=0;b<nblocks;b++) s += scratch[b*128 + j];
  accs[j] = s;
  __syncthreads();
  if (j < 64){
    float m = accs[j]*invN;
    float var = accs[j+64]*invN - m*m;
    stats[j] = m;
    stats[64+j] = rsqrtf(var + BN_EPS);
  }
}

// ---------------- final BN apply: bf16 P -> f32 out ----------------
__global__ __launch_bounds__(256) void bn_apply_k(const u32* __restrict__ P2, const float* __restrict__ stats,
                                                  float4* __restrict__ out, int nq){
  int t = blockIdx.x*256 + threadIdx.x;
  if (t >= nq) return;
  int l = (t*4) & 63;
  u32 v0 = P2[t*2], v1 = P2[t*2+1];
  float4 r;
  r.x = (__uint_as_float((v0 & 0xffffu) << 16) - stats[l+0]) * stats[64+l+0];
  r.y = (__uint_as_float( v0 & 0xffff0000u    ) - stats[l+1]) * stats[64+l+1];
  r.z = (__uint_as_float((v1 & 0xffffu) << 16) - stats[l+2]) * stats[64+l+2];
  r.w = (__uint_as_float( v1 & 0xffff0000u    ) - stats[l+3]) * stats[64+l+3];
  out[t] = r;
}

// ---------------- launcher ----------------
extern "C" void kernel_launch(void* const* d_in, const int* in_sizes, int n_in,
                              void* d_out, int out_size, void* d_ws, size_t ws_size,
                              hipStream_t stream)
{
  const float* x      = (const float*)d_in[0];
  const float* Wl[3]  = {(const float*)d_in[1], (const float*)d_in[7],  (const float*)d_in[13]};
  const float* asl[3] = {(const float*)d_in[2], (const float*)d_in[8],  (const float*)d_in[14]};
  const float* adl[3] = {(const float*)d_in[3], (const float*)d_in[9],  (const float*)d_in[15]};
  const float* bl[3]  = {(const float*)d_in[4], (const float*)d_in[10], (const float*)d_in[16]};
  const int*   el[3]  = {(const int*)d_in[5],   (const int*)d_in[11],   (const int*)d_in[17]};

  const int NS[4]  = {4096, 2048, 1024, 512};
  const int EPB[3] = {32768, 16384, 8192};
  const int LOG2NS[3] = {12, 11, 10};
  const int ECAP[3] = {32768+4*4096, 16384+4*2048, 8192+4*1024};  // 49152, 24576, 12288
  const int BATCH = 256;

  char* ws = (char*)d_ws;
  size_t off = 0;
  auto alloc = [&](size_t bytes)->char*{
    char* p = ws + off; off += (bytes + 255) & ~(size_t)255; return p;
  };

  u16*    hbuf    = (u16*)alloc((size_t)BATCH*NS[0]*64*2);            // 128 MB
  u16*    Pbuf    = (u16*)alloc((size_t)BATCH*NS[1]*64*2);            //  64 MB
  float2* alsq    = (float2*)alloc((size_t)BATCH*NS[0]*8);            //   8 MB (es, fs)
  float2* aldq    = (float2*)alloc((size_t)BATCH*NS[0]*8);            //   8 MB (ed, fd)
  float*  scratch = (float*)alloc(256*128*4);
  float*  stats   = (float*)alloc(128*4);
  u16*    wswz    = (u16*)alloc(10*64*8*2);
  float*  cvec    = (float*)alloc(128*4);
  int* counts_all = (int*)alloc((size_t)(NS[0]+NS[1]+NS[2])*4);
  int* cursor_all = (int*)alloc((size_t)(NS[0]+NS[1]+NS[2])*4);
  int *counts[3], *cursor[3], *indptr2[3];
  u16* ell_src[3];
  u16* perm[3];
  counts[0]=counts_all; counts[1]=counts_all+NS[0]; counts[2]=counts_all+NS[0]+NS[1];
  cursor[0]=cursor_all; cursor[1]=cursor_all+NS[0]; cursor[2]=cursor_all+NS[0]+NS[1];
  for (int i=0;i<3;i++){
    indptr2[i] = (int*)alloc((size_t)(NS[i]+1)*4);
    ell_src[i] = (u16*)alloc((size_t)(ECAP[i]+16)*2);
    perm[i]    = (u16*)alloc((size_t)NS[i]);      // NS/2 pairs * 2B
  }
  if (off > ws_size) return;

  // ---- build ----
  int ctot = NS[0]+NS[1]+NS[2];
  {
    dim3 ginit((ECAP[0]+16+255)/256, 4);
    init_k<<<ginit, 256, 0, stream>>>(counts_all, ell_src[0], ell_src[1], ell_src[2],
                                      ctot, ECAP[0]+16, ECAP[1]+16, ECAP[2]+16);
    dim3 ghist(EPB[0]/256, 3);
    hist_all_k<<<ghist, 256, 0, stream>>>(el[0], el[1], el[2], counts[0], counts[1], counts[2],
                                          EPB[0], EPB[1], EPB[2]);
    scan_all_k<<<3, 1024, 0, stream>>>(counts[0], counts[1], counts[2],
                                       indptr2[0], indptr2[1], indptr2[2],
                                       cursor[0], cursor[1], cursor[2],
                                       ell_src[0], ell_src[1], ell_src[2],
                                       NS[0], NS[1], NS[2]);
    scatter_all_k<<<ghist, 256, 0, stream>>>(el[0], el[1], el[2],
                                             cursor[0], cursor[1], cursor[2],
                                             ell_src[0], ell_src[1], ell_src[2],
                                             EPB[0], EPB[1], EPB[2]);
    pairsort_k<<<3, 1024, 0, stream>>>(counts[0], counts[1], counts[2],
                                       perm[0], perm[1], perm[2],
                                       NS[0]/2, NS[1]/2, NS[2]/2);
  }

  // ---- layers ----
  for (int i=0;i<3;i++){
    int ntot = BATCH*NS[i];

    if (i==0){
      gemm3_k<<<1024, 256, 0, stream>>>(x, Wl[0], asl[0], adl[0], hbuf, alsq, aldq, ntot/8);
    } else {
      float invN = 1.0f / (float)(BATCH*NS[i]);   // prev pooled rows = BATCH*NS[i-1]/2 = BATCH*NS[i]
      prep_w_k<<<1, 128, 0, stream>>>(Wl[i], asl[i], adl[i], scratch, invN, wswz, cvec);
      gemm64_mfma_k<<<2048, 256, 0, stream>>>(Pbuf, wswz, cvec, hbuf, alsq, aldq, ntot/16);
    }

    int nwaves = ntot/8;
    gat_pool_k<<<nwaves/4, 256, 0, stream>>>(hbuf, bl[i], indptr2[i], counts[i], perm[i],
                                             ell_src[i], alsq, aldq,
                                             Pbuf, LOG2NS[i], nwaves);

    bn_stats_k<<<256, 256, 0, stream>>>(Pbuf, scratch, (ntot/2)/1024);
  }

  // final BN: finish stats of layer 2, then materialize into d_out
  bn_finish_k<<<1, 128, 0, stream>>>(scratch, stats, 256, 1.0f/(float)(BATCH*NS[3]));
  int nq = out_size/4;
  bn_apply_k<<<(nq+255)/256, 256, 0, stream>>>((const u32*)Pbuf, stats, (float4*)d_out, nq);
}

// Round 12
// 567.006 us; speedup vs baseline: 1.0127x; 1.0099x over previous
//
#include <hip/hip_runtime.h>
#include <stdint.h>

#define NEG_SLOPE 0.2f
#define BN_EPS 1e-5f

typedef unsigned short u16;
typedef unsigned int   u32;
typedef __attribute__((ext_vector_type(2))) float  v2f;
typedef __attribute__((ext_vector_type(4))) float  f32x4;
typedef __attribute__((ext_vector_type(8))) short  short8;

__device__ __forceinline__ float bf2f(u16 u){ return __uint_as_float(((u32)u) << 16); }
__device__ __forceinline__ u16 f2bf(float f){           // round-to-nearest-even
  u32 u = __float_as_uint(f);
  return (u16)((u + 0x7fffu + ((u >> 16) & 1u)) >> 16);
}

// ---------------- build phase ----------------
// y=0: zero counts; y=1..3: fill ell_src[L] with 0xFFFF
__global__ __launch_bounds__(256) void init_k(int* __restrict__ counts, u16* __restrict__ s0,
                                              u16* __restrict__ s1, u16* __restrict__ s2,
                                              int nc, int n0, int n1, int n2){
  int t = blockIdx.x*256 + threadIdx.x;
  int y = blockIdx.y;
  if (y==0){ if (t<nc) counts[t]=0; }
  else {
    u16* sd = (y==1)?s0:(y==2)?s1:s2;
    int n   = (y==1)?n0:(y==2)?n1:n2;
    if (t<n) sd[t]=0xFFFFu;
  }
}

__global__ __launch_bounds__(256) void hist_all_k(const int* __restrict__ el0, const int* __restrict__ el1,
                                                  const int* __restrict__ el2, int* __restrict__ c0,
                                                  int* __restrict__ c1, int* __restrict__ c2,
                                                  int n0, int n1, int n2){
  int t = blockIdx.x*256 + threadIdx.x;
  int L = blockIdx.y;
  const int* dst = (L==0)?(el0+n0):(L==1)?(el1+n1):(el2+n2);
  int* counts    = (L==0)?c0:(L==1)?c1:c2;
  int n          = (L==0)?n0:(L==1)?n1:n2;
  if (t < n) atomicAdd(&counts[dst[t]], 1);
}

// padded scan per layer: row len = (deg+4)&~3 (>= deg+1), self at slot 0
// also writes ell_dst (owner row id) for the self slot
__global__ __launch_bounds__(1024) void scan_all_k(int* __restrict__ c0, int* __restrict__ c1, int* __restrict__ c2,
                         int* __restrict__ ip0, int* __restrict__ ip1, int* __restrict__ ip2,
                         int* __restrict__ cu0, int* __restrict__ cu1, int* __restrict__ cu2,
                         u16* __restrict__ sd0, u16* __restrict__ sd1, u16* __restrict__ sd2,
                         u16* __restrict__ dd0, u16* __restrict__ dd1, u16* __restrict__ dd2,
                         int n0, int n1, int n2){
  int L = blockIdx.x;
  const int* counts = (L==0)?c0:(L==1)?c1:c2;
  int* indptr2      = (L==0)?ip0:(L==1)?ip1:ip2;
  int* cursor       = (L==0)?cu0:(L==1)?cu1:cu2;
  u16* ell_src      = (L==0)?sd0:(L==1)?sd1:sd2;
  u16* ell_dst      = (L==0)?dd0:(L==1)?dd1:dd2;
  int n             = (L==0)?n0:(L==1)?n1:n2;
  __shared__ int part[1024];
  int tid = threadIdx.x;
  int base = tid*4;
  int v0=0,v1=0,v2=0,v3=0;
  if (base+0<n) v0 = (counts[base+0]+4)&~3;
  if (base+1<n) v1 = (counts[base+1]+4)&~3;
  if (base+2<n) v2 = (counts[base+2]+4)&~3;
  if (base+3<n) v3 = (counts[base+3]+4)&~3;
  part[tid] = v0+v1+v2+v3;
  __syncthreads();
  for (int off=1; off<1024; off<<=1){
    int t2 = (tid>=off)?part[tid-off]:0;
    __syncthreads();
    part[tid] += t2;
    __syncthreads();
  }
  int run = (tid>0)?part[tid-1]:0;
  if (base+0<n){ indptr2[base+0]=run; cursor[base+0]=run+1; ell_src[run]=(u16)(base+0); ell_dst[run]=(u16)(base+0); run+=v0; }
  if (base+1<n){ indptr2[base+1]=run; cursor[base+1]=run+1; ell_src[run]=(u16)(base+1); ell_dst[run]=(u16)(base+1); run+=v1; }
  if (base+2<n){ indptr2[base+2]=run; cursor[base+2]=run+1; ell_src[run]=(u16)(base+2); ell_dst[run]=(u16)(base+2); run+=v2; }
  if (base+3<n){ indptr2[base+3]=run; cursor[base+3]=run+1; ell_src[run]=(u16)(base+3); ell_dst[run]=(u16)(base+3); run+=v3; }
  if (tid==0) indptr2[n] = part[1023];
}

__global__ __launch_bounds__(256) void scatter_all_k(const int* __restrict__ el0, const int* __restrict__ el1,
                         const int* __restrict__ el2, int* __restrict__ cu0, int* __restrict__ cu1,
                         int* __restrict__ cu2, u16* __restrict__ sd0, u16* __restrict__ sd1,
                         u16* __restrict__ sd2, u16* __restrict__ dd0, u16* __restrict__ dd1,
                         u16* __restrict__ dd2, int n0, int n1, int n2){
  int t = blockIdx.x*256 + threadIdx.x;
  int L = blockIdx.y;
  const int* el = (L==0)?el0:(L==1)?el1:el2;
  int* cursor   = (L==0)?cu0:(L==1)?cu1:cu2;
  u16* ell_src  = (L==0)?sd0:(L==1)?sd1:sd2;
  u16* ell_dst  = (L==0)?dd0:(L==1)?dd1:dd2;
  int n         = (L==0)?n0:(L==1)?n1:n2;
  if (t < n){
    int dd = el[n + t];
    int p = atomicAdd(&cursor[dd], 1);
    ell_src[p] = (u16)el[t];
    ell_dst[p] = (u16)dd;
  }
}

// counting sort of pool-pairs by max(deg) -> perm (shared by all graphs)
__global__ __launch_bounds__(1024) void pairsort_k(const int* __restrict__ c0, const int* __restrict__ c1,
                         const int* __restrict__ c2, u16* __restrict__ pm0, u16* __restrict__ pm1,
                         u16* __restrict__ pm2, int np0, int np1, int np2){
  int L = blockIdx.x;
  const int* counts = (L==0)?c0:(L==1)?c1:c2;
  u16* perm = (L==0)?pm0:(L==1)?pm1:pm2;
  int np    = (L==0)?np0:(L==1)?np1:np2;
  __shared__ int hist[64];
  __shared__ int pos[64];
  int t = threadIdx.x;
  if (t < 64) hist[t] = 0;
  __syncthreads();
  for (int p=t; p<np; p+=1024){
    int k = min(max(counts[2*p], counts[2*p+1]), 63);
    atomicAdd(&hist[k], 1);
  }
  __syncthreads();
  if (t == 0){ int run=0; for (int i=0;i<64;i++){ pos[i]=run; run+=hist[i]; } }
  __syncthreads();
  for (int p=t; p<np; p+=1024){
    int k = min(max(counts[2*p], counts[2*p+1]), 63);
    int q = atomicAdd(&pos[k], 1);
    perm[q] = (u16)p;
  }
}

// ---------------- edge-softmax weights: LDS-staged per-graph als/ald ----------------
// One 1024-thread block per graph: stage als/ald (<=16KB each) into LDS, then stream
// ELL slots with LDS gathers (cheap) instead of L2 gathers (request-rate bound in r6's
// weight_k: 75us -> predicted ~14us total).
__global__ __launch_bounds__(1024) void weight_lds_k(const u16* __restrict__ ell_src,
                        const u16* __restrict__ ell_dst, const float* __restrict__ als,
                        const float* __restrict__ ald, _Float16* __restrict__ elw,
                        int log2NS, int ecap){
  __shared__ float sa[4096], sd[4096];
  const int g = blockIdx.x;
  const int NSg = 1 << log2NS;
  const int base = g << log2NS;
  for (int i = threadIdx.x; i < NSg; i += 1024){
    sa[i] = als[base + i];
    sd[i] = ald[base + i];
  }
  __syncthreads();
  const int nmask = NSg - 1;
  _Float16* out = elw + (size_t)g * ecap;
  for (int slot = threadIdx.x; slot < ecap; slot += 1024){
    int m = ell_src[slot];
    int s = m & nmask;
    int d = ell_dst[slot] & nmask;   // garbage on padding -> clamped; w masked to 0 below
    float a = sa[s] + sd[d];
    float w = (m == 0xFFFF) ? 0.f : __expf(fmaxf(a, NEG_SLOPE*a));
    out[slot] = (_Float16)w;
  }
}

// ---------------- layer-0 GEMM: x[n,3] @ W0[3,64] -> h bf16, al_s, al_d ----------------
__global__ __launch_bounds__(256) void gemm3_k(const float* __restrict__ x, const float* __restrict__ Wg,
                        const float* __restrict__ asrc, const float* __restrict__ adst,
                        u16* __restrict__ h, float* __restrict__ als, float* __restrict__ ald, int nrows8)
{
  const int l = threadIdx.x & 63;
  const int g = l >> 3;
  const int o = l & 7;
  float W0[8], W1[8], W2[8];
  float vs0=0.f,vs1=0.f,vs2=0.f,vd0=0.f,vd1=0.f,vd2=0.f;
  #pragma unroll
  for (int j=0;j<8;j++){
    W0[j] = Wg[      o*8 + j];
    W1[j] = Wg[ 64 + o*8 + j];
    W2[j] = Wg[128 + o*8 + j];
    float as = asrc[o*8 + j], ad = adst[o*8 + j];
    vs0 = fmaf(W0[j], as, vs0); vs1 = fmaf(W1[j], as, vs1); vs2 = fmaf(W2[j], as, vs2);
    vd0 = fmaf(W0[j], ad, vd0); vd1 = fmaf(W1[j], ad, vd1); vd2 = fmaf(W2[j], ad, vd2);
  }
  #pragma unroll
  for (int off=1; off<8; off<<=1){
    vs0 += __shfl_xor(vs0,off); vs1 += __shfl_xor(vs1,off); vs2 += __shfl_xor(vs2,off);
    vd0 += __shfl_xor(vd0,off); vd1 += __shfl_xor(vd1,off); vd2 += __shfl_xor(vd2,off);
  }
  int wv = blockIdx.x*4 + (int)(threadIdx.x>>6);
  int stride = gridDim.x*4;
  for (int blk = wv; blk < nrows8; blk += stride){
    int r = blk*8 + g;
    float x0 = x[(size_t)r*3+0];
    float x1 = x[(size_t)r*3+1];
    float x2 = x[(size_t)r*3+2];
    u32 pk[4];
    #pragma unroll
    for (int j=0;j<8;j+=2){
      float a0 = fmaf(x0, W0[j],   fmaf(x1, W1[j],   x2*W2[j]));
      float a1 = fmaf(x0, W0[j+1], fmaf(x1, W1[j+1], x2*W2[j+1]));
      pk[j>>1] = (u32)f2bf(a0) | ((u32)f2bf(a1) << 16);
    }
    ((int4*)(h + ((size_t)r << 6)))[o] = make_int4((int)pk[0],(int)pk[1],(int)pk[2],(int)pk[3]);
    if (o == 0){
      als[r] = fmaf(x2, vs2, fmaf(x1, vs1, x0*vs0));
      ald[r] = fmaf(x2, vd2, fmaf(x1, vd1, x0*vd0));
    }
  }
}

// ---------------- prep (layers 1/2): BN finish of prev layer + W' frags + als/ald B-tile ----------------
__global__ __launch_bounds__(128) void prep_w_k(const float* __restrict__ W, const float* __restrict__ asrc,
                        const float* __restrict__ adst, const float* __restrict__ scratch, float invN,
                        u16* __restrict__ wswz, float* __restrict__ cvec){
  __shared__ float mean_s[64], rstd_s[64], vs_s[64], vd_s[64], cv_s[64], acc[128];
  int t = threadIdx.x;
  float s = 0.f;
  #pragma unroll 8
  for (int b2=0;b2<256;b2++) s += scratch[b2*128 + t];
  acc[t] = s;
  __syncthreads();
  if (t < 64){
    float m = acc[t]*invN;
    float var = acc[64+t]*invN - m*m;
    mean_s[t] = m; rstd_s[t] = rsqrtf(var + BN_EPS);
  }
  __syncthreads();
  if (t < 64){
    float c = 0.f;
    for (int k=0;k<64;k++) c = fmaf(mean_s[k]*rstd_s[k], W[k*64+t], c);
    cv_s[t] = c; cvec[t] = c;
    float vs = 0.f, vd = 0.f;
    for (int col=0; col<64; col++){
      float wv = W[t*64+col];
      vs = fmaf(wv, asrc[col], vs);
      vd = fmaf(wv, adst[col], vd);
    }
    vs_s[t] = rstd_s[t]*vs; vd_s[t] = rstd_s[t]*vd;
  }
  __syncthreads();
  if (t == 0){
    float cs=0.f, cd=0.f;
    for (int col=0; col<64; col++){ cs = fmaf(cv_s[col], asrc[col], cs); cd = fmaf(cv_s[col], adst[col], cd); }
    cvec[64] = cs; cvec[65] = cd;
  }
  if (t < 64){
    #pragma unroll
    for (int f=0; f<8; f++){
      int tt = f >> 1, ch = f & 1;
      #pragma unroll
      for (int j=0; j<8; j++){
        int k   = ch*32 + (t>>4)*8 + j;
        int col = tt*16 + (t&15);
        wswz[(f*64 + t)*8 + j] = f2bf(rstd_s[k] * W[k*64 + col]);
      }
    }
    #pragma unroll
    for (int f=8; f<10; f++){
      int ch = f - 8;
      #pragma unroll
      for (int j=0; j<8; j++){
        int k = ch*32 + (t>>4)*8 + j;
        int colp = t & 15;
        float val = (colp==0)? vs_s[k] : (colp==1)? vd_s[k] : 0.f;
        wswz[(f*64 + t)*8 + j] = f2bf(val);
      }
    }
  }
}

// ---------------- layers 1/2 GEMM via MFMA: h = P @ W' - c; als/ald via augmented B-tile ----------------
__global__ __launch_bounds__(256) void gemm64_mfma_k(const u16* __restrict__ Pin, const u16* __restrict__ wswz,
                        const float* __restrict__ cvec,
                        u16* __restrict__ h, float* __restrict__ als, float* __restrict__ ald, int nblk16)
{
  const int l = threadIdx.x & 63;
  const int q = l >> 4;
  const int c = l & 15;
  short8 B[10];
  const int4* wsw = (const int4*)wswz;
  #pragma unroll
  for (int f=0; f<10; f++){
    int4 v = wsw[f*64 + l];
    B[f] = *(short8*)&v;
  }
  float cl[4];
  #pragma unroll
  for (int t=0;t<4;t++) cl[t] = cvec[t*16+c];
  const float const_s = cvec[64], const_d = cvec[65];
  int gw = blockIdx.x*4 + (int)(threadIdx.x>>6);
  int stride = gridDim.x*4;
  for (int blk = gw; blk < nblk16; blk += stride){
    size_t rowbase = (size_t)blk*16;
    const int4* arow = (const int4*)(Pin + (rowbase + c)*64);
    int4 a0v = arow[q];
    int4 a1v = arow[4+q];
    short8 A0 = *(short8*)&a0v, A1 = *(short8*)&a1v;
    f32x4 C0={0.f,0.f,0.f,0.f}, C1=C0, C2=C0, C3=C0, C4=C0;
    C0 = __builtin_amdgcn_mfma_f32_16x16x32_bf16(A0, B[0], C0, 0,0,0);
    C0 = __builtin_amdgcn_mfma_f32_16x16x32_bf16(A1, B[1], C0, 0,0,0);
    C1 = __builtin_amdgcn_mfma_f32_16x16x32_bf16(A0, B[2], C1, 0,0,0);
    C1 = __builtin_amdgcn_mfma_f32_16x16x32_bf16(A1, B[3], C1, 0,0,0);
    C2 = __builtin_amdgcn_mfma_f32_16x16x32_bf16(A0, B[4], C2, 0,0,0);
    C2 = __builtin_amdgcn_mfma_f32_16x16x32_bf16(A1, B[5], C2, 0,0,0);
    C3 = __builtin_amdgcn_mfma_f32_16x16x32_bf16(A0, B[6], C3, 0,0,0);
    C3 = __builtin_amdgcn_mfma_f32_16x16x32_bf16(A1, B[7], C3, 0,0,0);
    C4 = __builtin_amdgcn_mfma_f32_16x16x32_bf16(A0, B[8], C4, 0,0,0);
    C4 = __builtin_amdgcn_mfma_f32_16x16x32_bf16(A1, B[9], C4, 0,0,0);
    #pragma unroll
    for (int t=0;t<4;t++){
      f32x4 C = (t==0)?C0:(t==1)?C1:(t==2)?C2:C3;
      #pragma unroll
      for (int reg=0;reg<4;reg++){
        h[(rowbase + q*4 + reg)*64 + t*16 + c] = f2bf(C[reg] - cl[t]);
      }
    }
    if (c == 0){
      #pragma unroll
      for (int reg=0;reg<4;reg++) als[rowbase + q*4 + reg] = C4[reg] - const_s;
    } else if (c == 1){
      #pragma unroll
      for (int reg=0;reg<4;reg++) ald[rowbase + q*4 + reg] = C4[reg] - const_d;
    }
  }
}

// ---------------- GAT gather + precomputed-weight softmax + bias + relu + pairwise max-pool ----------------
// wave = 8 groups x 8 lanes; group g owns node 2*perm[pairslot]+(g&1).
// 3-deep software pipeline on {meta, h-row, w}. Weight read from elw (f16, streaming
// address per group, 0 on padding slots) -- the r6 configuration measured at 112us L0
// (VALU 85us, stall 27us), the best gat variant of the session.
__global__ __launch_bounds__(256) void gat_pool_k(const u16* __restrict__ h, const float* __restrict__ bias,
                      const int* __restrict__ indptr2, const int* __restrict__ counts,
                      const u16* __restrict__ perm, const u16* __restrict__ ell_src,
                      const _Float16* __restrict__ elw,
                      u16* __restrict__ P, int log2NS, int ecap, int nwaves)
{
  const int l = threadIdx.x & 63;
  const int g = l >> 3;
  const int o = l & 7;
  const int NB  = gridDim.x;
  const int bid = blockIdx.x;
  const int lb  = (bid & 7) * (NB >> 3) + (bid >> 3);   // XCD swizzle
  const int wv  = lb * 4 + (int)(threadIdx.x >> 6);
  if (wv >= nwaves) return;
  const int wvu = __builtin_amdgcn_readfirstlane(wv);   // wave-uniform -> SGPR-based addressing

  const int wbits = log2NS - 3;
  const int b    = wvu >> wbits;
  const int widx = wvu & ((1 << wbits) - 1);
  const int pairslot = widx*4 + (g >> 1);
  const int prow = perm[pairslot];
  const int d = 2*prow + (g & 1);
  const int nmask = (1 << log2NS) - 1;
  const int base = b << log2NS;

  const char* __restrict__ hbase  = (const char*)(h + ((size_t)base << 6));     // uniform
  const char* __restrict__ elb    = (const char*)ell_src;                       // uniform
  const char* __restrict__ wbase  = (const char*)(elw + (size_t)b * ecap);      // uniform
  const u32 olane16 = (u32)o << 4;

  const int p0  = indptr2[d];
  const int cnt = counts[d] + 1;
  const u32 moff = (u32)p0 << 1;     // byte offset: same for ell_src and elw (2B/slot)

  v2f a01={0.f,0.f}, a23={0.f,0.f}, a45={0.f,0.f}, a67={0.f,0.f};
  float z = 0.f;

  // prologue: meta for item 2; h+w for items 0,1
  u32 s0 = (u32)(*(const u16*)(elb + moff)) & nmask;
  int4 H0 = *(const int4*)(hbase + ((s0 << 7) + olane16));
  float w0f = (float)*(const _Float16*)(wbase + moff);
  u32 s1 = (u32)(*(const u16*)(elb + moff + 2)) & nmask;
  int4 H1 = *(const int4*)(hbase + ((s1 << 7) + olane16));
  float w1f = (float)*(const _Float16*)(wbase + moff + 2);
  int m2 = *(const u16*)(elb + moff + 4);

  #pragma unroll 4
  for (int it = 0; it < cnt; ++it){
    // issue h+w for item it+2
    u32 s2 = (u32)m2 & nmask;
    int4 Hn = *(const int4*)(hbase + ((s2 << 7) + olane16));
    float w2f = (float)*(const _Float16*)(wbase + (moff + ((u32)(it + 2) << 1)));
    // meta for item it+3
    int m3 = *(const u16*)(elb + (moff + ((u32)(it + 3) << 1)));
    // consume item it
    z += w0f;
    v2f w2 = {w0f, w0f};
    a01 += (v2f){ __uint_as_float(((u32)H0.x) << 16), __uint_as_float(((u32)H0.x) & 0xffff0000u) } * w2;
    a23 += (v2f){ __uint_as_float(((u32)H0.y) << 16), __uint_as_float(((u32)H0.y) & 0xffff0000u) } * w2;
    a45 += (v2f){ __uint_as_float(((u32)H0.z) << 16), __uint_as_float(((u32)H0.z) & 0xffff0000u) } * w2;
    a67 += (v2f){ __uint_as_float(((u32)H0.w) << 16), __uint_as_float(((u32)H0.w) & 0xffff0000u) } * w2;
    // shift pipeline (erased by unroll + copy-prop)
    m2 = m3;
    H0 = H1; H1 = Hn;
    w0f = w1f; w1f = w2f;
  }

  float rz = __builtin_amdgcn_rcpf(z);
  const float* bp = bias + (o << 3);          // loaded after the loop: not live across it
  float4 bA = *(const float4*)(bp);
  float4 bB = *(const float4*)(bp + 4);
  float q0 = fmaxf(fmaf(a01.x, rz, bA.x), 0.f);
  float q1 = fmaxf(fmaf(a01.y, rz, bA.y), 0.f);
  float q2 = fmaxf(fmaf(a23.x, rz, bA.z), 0.f);
  float q3 = fmaxf(fmaf(a23.y, rz, bA.w), 0.f);
  float q4 = fmaxf(fmaf(a45.x, rz, bB.x), 0.f);
  float q5 = fmaxf(fmaf(a45.y, rz, bB.y), 0.f);
  float q6 = fmaxf(fmaf(a67.x, rz, bB.z), 0.f);
  float q7 = fmaxf(fmaf(a67.y, rz, bB.w), 0.f);
  q0 = fmaxf(q0, __shfl_xor(q0, 8));
  q1 = fmaxf(q1, __shfl_xor(q1, 8));
  q2 = fmaxf(q2, __shfl_xor(q2, 8));
  q3 = fmaxf(q3, __shfl_xor(q3, 8));
  q4 = fmaxf(q4, __shfl_xor(q4, 8));
  q5 = fmaxf(q5, __shfl_xor(q5, 8));
  q6 = fmaxf(q6, __shfl_xor(q6, 8));
  q7 = fmaxf(q7, __shfl_xor(q7, 8));
  if ((g & 1) == 0){
    u32 w0 = (u32)f2bf(q0) | ((u32)f2bf(q1) << 16);
    u32 w1 = (u32)f2bf(q2) | ((u32)f2bf(q3) << 16);
    u32 w2p = (u32)f2bf(q4) | ((u32)f2bf(q5) << 16);
    u32 w3 = (u32)f2bf(q6) | ((u32)f2bf(q7) << 16);
    char* Pb = (char*)P + (((size_t)b << (log2NS - 1)) << 7);   // uniform base
    *(int4*)(Pb + (((u32)prow << 7) + olane16)) = make_int4((int)w0,(int)w1,(int)w2p,(int)w3);
  }
}

// ---------------- BatchNorm stats (stage 1) ----------------
__global__ __launch_bounds__(256) void bn_stats_k(const u16* __restrict__ P, float* __restrict__ scratch, int iters){
  const int l = threadIdx.x & 63;
  int gw = blockIdx.x*4 + (threadIdx.x>>6);
  int GW = gridDim.x*4;
  float s = 0.f, s2 = 0.f;
  #pragma unroll 4
  for (int i = 0; i < iters; i++){
    int r = gw + i*GW;
    float v = bf2f(P[(size_t)r*64 + l]);
    s += v; s2 = fmaf(v, v, s2);
  }
  __shared__ float ls[256], ls2[256];
  ls[threadIdx.x] = s; ls2[threadIdx.x] = s2;
  __syncthreads();
  if (threadIdx.x < 64){
    float S  = ls[threadIdx.x] + ls[threadIdx.x+64] + ls[threadIdx.x+128] + ls[threadIdx.x+192];
    float S2 = ls2[threadIdx.x] + ls2[threadIdx.x+64] + ls2[threadIdx.x+128] + ls2[threadIdx.x+192];
    scratch[blockIdx.x*128 + threadIdx.x] = S;
    scratch[blockIdx.x*128 + 64 + threadIdx.x] = S2;
  }
}

__global__ __launch_bounds__(128) void bn_finish_k(const float* __restrict__ scratch, float* __restrict__ stats,
                                                   int nblocks, float invN){
  __shared__ float accs[128];
  int j = threadIdx.x;
  float s = 0.f;
  #pragma unroll 8
  for (int b=0;b<nblocks;b++) s += scratch[b*128 + j];
  accs[j] = s;
  __syncthreads();
  if (j < 64){
    float m = accs[j]*invN;
    float var = accs[j+64]*invN - m*m;
    stats[j] = m;
    stats[64+j] = rsqrtf(var + BN_EPS);
  }
}

// ---------------- final BN apply: bf16 P -> f32 out ----------------
__global__ __launch_bounds__(256) void bn_apply_k(const u32* __restrict__ P2, const float* __restrict__ stats,
                                                  float4* __restrict__ out, int nq){
  int t = blockIdx.x*256 + threadIdx.x;
  if (t >= nq) return;
  int l = (t*4) & 63;
  u32 v0 = P2[t*2], v1 = P2[t*2+1];
  float4 r;
  r.x = (__uint_as_float((v0 & 0xffffu) << 16) - stats[l+0]) * stats[64+l+0];
  r.y = (__uint_as_float( v0 & 0xffff0000u    ) - stats[l+1]) * stats[64+l+1];
  r.z = (__uint_as_float((v1 & 0xffffu) << 16) - stats[l+2]) * stats[64+l+2];
  r.w = (__uint_as_float( v1 & 0xffff0000u    ) - stats[l+3]) * stats[64+l+3];
  out[t] = r;
}

// ---------------- launcher ----------------
extern "C" void kernel_launch(void* const* d_in, const int* in_sizes, int n_in,
                              void* d_out, int out_size, void* d_ws, size_t ws_size,
                              hipStream_t stream)
{
  const float* x      = (const float*)d_in[0];
  const float* Wl[3]  = {(const float*)d_in[1], (const float*)d_in[7],  (const float*)d_in[13]};
  const float* asl[3] = {(const float*)d_in[2], (const float*)d_in[8],  (const float*)d_in[14]};
  const float* adl[3] = {(const float*)d_in[3], (const float*)d_in[9],  (const float*)d_in[15]};
  const float* bl[3]  = {(const float*)d_in[4], (const float*)d_in[10], (const float*)d_in[16]};
  const int*   el[3]  = {(const int*)d_in[5],   (const int*)d_in[11],   (const int*)d_in[17]};

  const int NS[4]  = {4096, 2048, 1024, 512};
  const int EPB[3] = {32768, 16384, 8192};
  const int LOG2NS[3] = {12, 11, 10};
  const int ECAP[3] = {32768+4*4096, 16384+4*2048, 8192+4*1024};  // 49152, 24576, 12288
  const int BATCH = 256;

  char* ws = (char*)d_ws;
  size_t off = 0;
  auto alloc = [&](size_t bytes)->char*{
    char* p = ws + off; off += (bytes + 255) & ~(size_t)255; return p;
  };

  u16*   hbuf    = (u16*)alloc((size_t)BATCH*NS[0]*64*2);            // 128 MB
  u16*   Pbuf    = (u16*)alloc((size_t)BATCH*NS[1]*64*2);            //  64 MB
  float* als     = (float*)alloc((size_t)BATCH*NS[0]*4);             //   4 MB
  float* ald     = (float*)alloc((size_t)BATCH*NS[0]*4);             //   4 MB
  u16*   elw     = (u16*)alloc(((size_t)BATCH*ECAP[0] + 16)*2);      //  25.2 MB (f16 edge weights)
  float* scratch = (float*)alloc(256*128*4);
  float* stats   = (float*)alloc(128*4);
  u16*   wswz    = (u16*)alloc(10*64*8*2);
  float* cvec    = (float*)alloc(128*4);
  int* counts_all = (int*)alloc((size_t)(NS[0]+NS[1]+NS[2])*4);
  int* cursor_all = (int*)alloc((size_t)(NS[0]+NS[1]+NS[2])*4);
  int *counts[3], *cursor[3], *indptr2[3];
  u16* ell_src[3];
  u16* ell_dst[3];
  u16* perm[3];
  counts[0]=counts_all; counts[1]=counts_all+NS[0]; counts[2]=counts_all+NS[0]+NS[1];
  cursor[0]=cursor_all; cursor[1]=cursor_all+NS[0]; cursor[2]=cursor_all+NS[0]+NS[1];
  for (int i=0;i<3;i++){
    indptr2[i] = (int*)alloc((size_t)(NS[i]+1)*4);
    ell_src[i] = (u16*)alloc((size_t)(ECAP[i]+16)*2);
    ell_dst[i] = (u16*)alloc((size_t)(ECAP[i]+16)*2);
    perm[i]    = (u16*)alloc((size_t)NS[i]);      // NS/2 pairs * 2B
  }
  if (off > ws_size) return;

  // ---- build ----
  int ctot = NS[0]+NS[1]+NS[2];
  {
    dim3 ginit((ECAP[0]+16+255)/256, 4);
    init_k<<<ginit, 256, 0, stream>>>(counts_all, ell_src[0], ell_src[1], ell_src[2],
                                      ctot, ECAP[0]+16, ECAP[1]+16, ECAP[2]+16);
    dim3 ghist(EPB[0]/256, 3);
    hist_all_k<<<ghist, 256, 0, stream>>>(el[0], el[1], el[2], counts[0], counts[1], counts[2],
                                          EPB[0], EPB[1], EPB[2]);
    scan_all_k<<<3, 1024, 0, stream>>>(counts[0], counts[1], counts[2],
                                       indptr2[0], indptr2[1], indptr2[2],
                                       cursor[0], cursor[1], cursor[2],
                                       ell_src[0], ell_src[1], ell_src[2],
                                       ell_dst[0], ell_dst[1], ell_dst[2],
                                       NS[0], NS[1], NS[2]);
    scatter_all_k<<<ghist, 256, 0, stream>>>(el[0], el[1], el[2],
                                             cursor[0], cursor[1], cursor[2],
                                             ell_src[0], ell_src[1], ell_src[2],
                                             ell_dst[0], ell_dst[1], ell_dst[2],
                                             EPB[0], EPB[1], EPB[2]);
    pairsort_k<<<3, 1024, 0, stream>>>(counts[0], counts[1], counts[2],
                                       perm[0], perm[1], perm[2],
                                       NS[0]/2, NS[1]/2, NS[2]/2);
  }

  // ---- layers ----
  for (int i=0;i<3;i++){
    int ntot = BATCH*NS[i];

    if (i==0){
      gemm3_k<<<1024, 256, 0, stream>>>(x, Wl[0], asl[0], adl[0], hbuf, als, ald, ntot/8);
    } else {
      float invN = 1.0f / (float)(BATCH*NS[i]);   // prev pooled rows = BATCH*NS[i-1]/2 = BATCH*NS[i]
      prep_w_k<<<1, 128, 0, stream>>>(Wl[i], asl[i], adl[i], scratch, invN, wswz, cvec);
      gemm64_mfma_k<<<2048, 256, 0, stream>>>(Pbuf, wswz, cvec, hbuf, als, ald, ntot/16);
    }

    // edge-softmax weights: LDS-staged per-graph gathers (one block per graph)
    weight_lds_k<<<BATCH, 1024, 0, stream>>>(ell_src[i], ell_dst[i], als, ald,
                                             (_Float16*)elw, LOG2NS[i], ECAP[i]);

    int nwaves = ntot/8;
    gat_pool_k<<<nwaves/4, 256, 0, stream>>>(hbuf, bl[i], indptr2[i], counts[i], perm[i],
                                             ell_src[i], (const _Float16*)elw,
                                             Pbuf, LOG2NS[i], ECAP[i], nwaves);

    bn_stats_k<<<256, 256, 0, stream>>>(Pbuf, scratch, (ntot/2)/1024);
  }

  // final BN: finish stats of layer 2, then materialize into d_out
  bn_finish_k<<<1, 128, 0, stream>>>(scratch, stats, 256, 1.0f/(float)(BATCH*NS[3]));
  int nq = out_size/4;
  bn_apply_k<<<(nq+255)/256, 256, 0, stream>>>((const u32*)Pbuf, stats, (float4*)d_out, nq);
}

// Round 15
// 556.320 us; speedup vs baseline: 1.0322x; 1.0192x over previous
//
#include <hip/hip_runtime.h>
#include <stdint.h>

#define NEG_SLOPE 0.2f
#define BN_EPS 1e-5f

typedef unsigned short u16;
typedef unsigned int   u32;
typedef __attribute__((ext_vector_type(2))) float  v2f;
typedef __attribute__((ext_vector_type(4))) float  f32x4;
typedef __attribute__((ext_vector_type(8))) short  short8;

__device__ __forceinline__ float bf2f(u16 u){ return __uint_as_float(((u32)u) << 16); }
__device__ __forceinline__ u16 f2bf(float f){           // round-to-nearest-even
  u32 u = __float_as_uint(f);
  return (u16)((u + 0x7fffu + ((u >> 16) & 1u)) >> 16);
}

// ---------------- build phase ----------------
// y=0: zero counts; y=1..3: fill ell_src[L] with 0xFFFF
__global__ __launch_bounds__(256) void init_k(int* __restrict__ counts, u16* __restrict__ s0,
                                              u16* __restrict__ s1, u16* __restrict__ s2,
                                              int nc, int n0, int n1, int n2){
  int t = blockIdx.x*256 + threadIdx.x;
  int y = blockIdx.y;
  if (y==0){ if (t<nc) counts[t]=0; }
  else {
    u16* sd = (y==1)?s0:(y==2)?s1:s2;
    int n   = (y==1)?n0:(y==2)?n1:n2;
    if (t<n) sd[t]=0xFFFFu;
  }
}

__global__ __launch_bounds__(256) void hist_all_k(const int* __restrict__ el0, const int* __restrict__ el1,
                                                  const int* __restrict__ el2, int* __restrict__ c0,
                                                  int* __restrict__ c1, int* __restrict__ c2,
                                                  int n0, int n1, int n2){
  int t = blockIdx.x*256 + threadIdx.x;
  int L = blockIdx.y;
  const int* dst = (L==0)?(el0+n0):(L==1)?(el1+n1):(el2+n2);
  int* counts    = (L==0)?c0:(L==1)?c1:c2;
  int n          = (L==0)?n0:(L==1)?n1:n2;
  if (t < n) atomicAdd(&counts[dst[t]], 1);
}

// padded scan per layer: row len = (deg+4)&~3 (>= deg+1), self at slot 0
// also writes ell_dst (owner row id) for the self slot
__global__ __launch_bounds__(1024) void scan_all_k(int* __restrict__ c0, int* __restrict__ c1, int* __restrict__ c2,
                         int* __restrict__ ip0, int* __restrict__ ip1, int* __restrict__ ip2,
                         int* __restrict__ cu0, int* __restrict__ cu1, int* __restrict__ cu2,
                         u16* __restrict__ sd0, u16* __restrict__ sd1, u16* __restrict__ sd2,
                         u16* __restrict__ dd0, u16* __restrict__ dd1, u16* __restrict__ dd2,
                         int n0, int n1, int n2){
  int L = blockIdx.x;
  const int* counts = (L==0)?c0:(L==1)?c1:c2;
  int* indptr2      = (L==0)?ip0:(L==1)?ip1:ip2;
  int* cursor       = (L==0)?cu0:(L==1)?cu1:cu2;
  u16* ell_src      = (L==0)?sd0:(L==1)?sd1:sd2;
  u16* ell_dst      = (L==0)?dd0:(L==1)?dd1:dd2;
  int n             = (L==0)?n0:(L==1)?n1:n2;
  __shared__ int part[1024];
  int tid = threadIdx.x;
  int base = tid*4;
  int v0=0,v1=0,v2=0,v3=0;
  if (base+0<n) v0 = (counts[base+0]+4)&~3;
  if (base+1<n) v1 = (counts[base+1]+4)&~3;
  if (base+2<n) v2 = (counts[base+2]+4)&~3;
  if (base+3<n) v3 = (counts[base+3]+4)&~3;
  part[tid] = v0+v1+v2+v3;
  __syncthreads();
  for (int off=1; off<1024; off<<=1){
    int t2 = (tid>=off)?part[tid-off]:0;
    __syncthreads();
    part[tid] += t2;
    __syncthreads();
  }
  int run = (tid>0)?part[tid-1]:0;
  if (base+0<n){ indptr2[base+0]=run; cursor[base+0]=run+1; ell_src[run]=(u16)(base+0); ell_dst[run]=(u16)(base+0); run+=v0; }
  if (base+1<n){ indptr2[base+1]=run; cursor[base+1]=run+1; ell_src[run]=(u16)(base+1); ell_dst[run]=(u16)(base+1); run+=v1; }
  if (base+2<n){ indptr2[base+2]=run; cursor[base+2]=run+1; ell_src[run]=(u16)(base+2); ell_dst[run]=(u16)(base+2); run+=v2; }
  if (base+3<n){ indptr2[base+3]=run; cursor[base+3]=run+1; ell_src[run]=(u16)(base+3); ell_dst[run]=(u16)(base+3); run+=v3; }
  if (tid==0) indptr2[n] = part[1023];
}

__global__ __launch_bounds__(256) void scatter_all_k(const int* __restrict__ el0, const int* __restrict__ el1,
                         const int* __restrict__ el2, int* __restrict__ cu0, int* __restrict__ cu1,
                         int* __restrict__ cu2, u16* __restrict__ sd0, u16* __restrict__ sd1,
                         u16* __restrict__ sd2, u16* __restrict__ dd0, u16* __restrict__ dd1,
                         u16* __restrict__ dd2, int n0, int n1, int n2){
  int t = blockIdx.x*256 + threadIdx.x;
  int L = blockIdx.y;
  const int* el = (L==0)?el0:(L==1)?el1:el2;
  int* cursor   = (L==0)?cu0:(L==1)?cu1:cu2;
  u16* ell_src  = (L==0)?sd0:(L==1)?sd1:sd2;
  u16* ell_dst  = (L==0)?dd0:(L==1)?dd1:dd2;
  int n         = (L==0)?n0:(L==1)?n1:n2;
  if (t < n){
    int dd = el[n + t];
    int p = atomicAdd(&cursor[dd], 1);
    ell_src[p] = (u16)el[t];
    ell_dst[p] = (u16)dd;
  }
}

// counting sort of pool-pairs by max(deg) -> perm (shared by all graphs)
__global__ __launch_bounds__(1024) void pairsort_k(const int* __restrict__ c0, const int* __restrict__ c1,
                         const int* __restrict__ c2, u16* __restrict__ pm0, u16* __restrict__ pm1,
                         u16* __restrict__ pm2, int np0, int np1, int np2){
  int L = blockIdx.x;
  const int* counts = (L==0)?c0:(L==1)?c1:c2;
  u16* perm = (L==0)?pm0:(L==1)?pm1:pm2;
  int np    = (L==0)?np0:(L==1)?np1:np2;
  __shared__ int hist[64];
  __shared__ int pos[64];
  int t = threadIdx.x;
  if (t < 64) hist[t] = 0;
  __syncthreads();
  for (int p=t; p<np; p+=1024){
    int k = min(max(counts[2*p], counts[2*p+1]), 63);
    atomicAdd(&hist[k], 1);
  }
  __syncthreads();
  if (t == 0){ int run=0; for (int i=0;i<64;i++){ pos[i]=run; run+=hist[i]; } }
  __syncthreads();
  for (int p=t; p<np; p+=1024){
    int k = min(max(counts[2*p], counts[2*p+1]), 63);
    int q = atomicAdd(&pos[k], 1);
    perm[q] = (u16)p;
  }
}

// ---------------- edge-softmax weights: LDS-staged, 4 blocks/graph for full occupancy ----------------
// r12 used 1 block(1024t)/graph = 8 waves/CU (25% occ) -> ~70us latency-bound.
// Now: 4 blocks x 512t per graph -> 4 blocks/CU = 2048 threads + 128KB LDS = full occupancy.
// Redundant staging (each block stages the whole graph) costs 32MB of L2-hot reads ~ 1us.
__global__ __launch_bounds__(512) void weight_lds_k(const u16* __restrict__ ell_src,
                        const u16* __restrict__ ell_dst, const float* __restrict__ als,
                        const float* __restrict__ ald, _Float16* __restrict__ elw,
                        int log2NS, int ecap){
  __shared__ float sa[4096], sd[4096];
  const int g = blockIdx.y;
  const int qb = blockIdx.x;
  const int NSg = 1 << log2NS;
  const int base = g << log2NS;
  for (int i = threadIdx.x; i < NSg; i += 512){
    sa[i] = als[base + i];
    sd[i] = ald[base + i];
  }
  __syncthreads();
  const int nmask = NSg - 1;
  const int chunk = ecap >> 2;          // ecap divisible by 4 for all layers
  const int lo = qb * chunk;
  const int hi = lo + chunk;
  _Float16* out = elw + (size_t)g * ecap;
  for (int slot = lo + threadIdx.x; slot < hi; slot += 512){
    int m = ell_src[slot];
    int s = m & nmask;
    int d = ell_dst[slot] & nmask;   // garbage on padding -> clamped; w masked to 0 below
    float a = sa[s] + sd[d];
    float w = (m == 0xFFFF) ? 0.f : __expf(fmaxf(a, NEG_SLOPE*a));
    out[slot] = (_Float16)w;
  }
}

// ---------------- layer-0 GEMM: x[n,3] @ W0[3,64] -> h bf16, al_s, al_d ----------------
__global__ __launch_bounds__(256) void gemm3_k(const float* __restrict__ x, const float* __restrict__ Wg,
                        const float* __restrict__ asrc, const float* __restrict__ adst,
                        u16* __restrict__ h, float* __restrict__ als, float* __restrict__ ald, int nrows8)
{
  const int l = threadIdx.x & 63;
  const int g = l >> 3;
  const int o = l & 7;
  float W0[8], W1[8], W2[8];
  float vs0=0.f,vs1=0.f,vs2=0.f,vd0=0.f,vd1=0.f,vd2=0.f;
  #pragma unroll
  for (int j=0;j<8;j++){
    W0[j] = Wg[      o*8 + j];
    W1[j] = Wg[ 64 + o*8 + j];
    W2[j] = Wg[128 + o*8 + j];
    float as = asrc[o*8 + j], ad = adst[o*8 + j];
    vs0 = fmaf(W0[j], as, vs0); vs1 = fmaf(W1[j], as, vs1); vs2 = fmaf(W2[j], as, vs2);
    vd0 = fmaf(W0[j], ad, vd0); vd1 = fmaf(W1[j], ad, vd1); vd2 = fmaf(W2[j], ad, vd2);
  }
  #pragma unroll
  for (int off=1; off<8; off<<=1){
    vs0 += __shfl_xor(vs0,off); vs1 += __shfl_xor(vs1,off); vs2 += __shfl_xor(vs2,off);
    vd0 += __shfl_xor(vd0,off); vd1 += __shfl_xor(vd1,off); vd2 += __shfl_xor(vd2,off);
  }
  int wv = blockIdx.x*4 + (int)(threadIdx.x>>6);
  int stride = gridDim.x*4;
  for (int blk = wv; blk < nrows8; blk += stride){
    int r = blk*8 + g;
    float x0 = x[(size_t)r*3+0];
    float x1 = x[(size_t)r*3+1];
    float x2 = x[(size_t)r*3+2];
    u32 pk[4];
    #pragma unroll
    for (int j=0;j<8;j+=2){
      float a0 = fmaf(x0, W0[j],   fmaf(x1, W1[j],   x2*W2[j]));
      float a1 = fmaf(x0, W0[j+1], fmaf(x1, W1[j+1], x2*W2[j+1]));
      pk[j>>1] = (u32)f2bf(a0) | ((u32)f2bf(a1) << 16);
    }
    ((int4*)(h + ((size_t)r << 6)))[o] = make_int4((int)pk[0],(int)pk[1],(int)pk[2],(int)pk[3]);
    if (o == 0){
      als[r] = fmaf(x2, vs2, fmaf(x1, vs1, x0*vs0));
      ald[r] = fmaf(x2, vd2, fmaf(x1, vd1, x0*vd0));
    }
  }
}

// ---------------- prep (layers 1/2): BN finish of prev layer + W' frags + als/ald B-tile ----------------
__global__ __launch_bounds__(128) void prep_w_k(const float* __restrict__ W, const float* __restrict__ asrc,
                        const float* __restrict__ adst, const float* __restrict__ scratch, float invN,
                        u16* __restrict__ wswz, float* __restrict__ cvec){
  __shared__ float mean_s[64], rstd_s[64], vs_s[64], vd_s[64], cv_s[64], acc[128];
  int t = threadIdx.x;
  float s = 0.f;
  #pragma unroll 8
  for (int b2=0;b2<256;b2++) s += scratch[b2*128 + t];
  acc[t] = s;
  __syncthreads();
  if (t < 64){
    float m = acc[t]*invN;
    float var = acc[64+t]*invN - m*m;
    mean_s[t] = m; rstd_s[t] = rsqrtf(var + BN_EPS);
  }
  __syncthreads();
  if (t < 64){
    float c = 0.f;
    for (int k=0;k<64;k++) c = fmaf(mean_s[k]*rstd_s[k], W[k*64+t], c);
    cv_s[t] = c; cvec[t] = c;
    float vs = 0.f, vd = 0.f;
    for (int col=0; col<64; col++){
      float wv = W[t*64+col];
      vs = fmaf(wv, asrc[col], vs);
      vd = fmaf(wv, adst[col], vd);
    }
    vs_s[t] = rstd_s[t]*vs; vd_s[t] = rstd_s[t]*vd;
  }
  __syncthreads();
  if (t == 0){
    float cs=0.f, cd=0.f;
    for (int col=0; col<64; col++){ cs = fmaf(cv_s[col], asrc[col], cs); cd = fmaf(cv_s[col], adst[col], cd); }
    cvec[64] = cs; cvec[65] = cd;
  }
  if (t < 64){
    #pragma unroll
    for (int f=0; f<8; f++){
      int tt = f >> 1, ch = f & 1;
      #pragma unroll
      for (int j=0; j<8; j++){
        int k   = ch*32 + (t>>4)*8 + j;
        int col = tt*16 + (t&15);
        wswz[(f*64 + t)*8 + j] = f2bf(rstd_s[k] * W[k*64 + col]);
      }
    }
    #pragma unroll
    for (int f=8; f<10; f++){
      int ch = f - 8;
      #pragma unroll
      for (int j=0; j<8; j++){
        int k = ch*32 + (t>>4)*8 + j;
        int colp = t & 15;
        float val = (colp==0)? vs_s[k] : (colp==1)? vd_s[k] : 0.f;
        wswz[(f*64 + t)*8 + j] = f2bf(val);
      }
    }
  }
}

// ---------------- layers 1/2 GEMM via MFMA: h = P @ W' - c; als/ald via augmented B-tile ----------------
__global__ __launch_bounds__(256) void gemm64_mfma_k(const u16* __restrict__ Pin, const u16* __restrict__ wswz,
                        const float* __restrict__ cvec,
                        u16* __restrict__ h, float* __restrict__ als, float* __restrict__ ald, int nblk16)
{
  const int l = threadIdx.x & 63;
  const int q = l >> 4;
  const int c = l & 15;
  short8 B[10];
  const int4* wsw = (const int4*)wswz;
  #pragma unroll
  for (int f=0; f<10; f++){
    int4 v = wsw[f*64 + l];
    B[f] = *(short8*)&v;
  }
  float cl[4];
  #pragma unroll
  for (int t=0;t<4;t++) cl[t] = cvec[t*16+c];
  const float const_s = cvec[64], const_d = cvec[65];
  int gw = blockIdx.x*4 + (int)(threadIdx.x>>6);
  int stride = gridDim.x*4;
  for (int blk = gw; blk < nblk16; blk += stride){
    size_t rowbase = (size_t)blk*16;
    const int4* arow = (const int4*)(Pin + (rowbase + c)*64);
    int4 a0v = arow[q];
    int4 a1v = arow[4+q];
    short8 A0 = *(short8*)&a0v, A1 = *(short8*)&a1v;
    f32x4 C0={0.f,0.f,0.f,0.f}, C1=C0, C2=C0, C3=C0, C4=C0;
    C0 = __builtin_amdgcn_mfma_f32_16x16x32_bf16(A0, B[0], C0, 0,0,0);
    C0 = __builtin_amdgcn_mfma_f32_16x16x32_bf16(A1, B[1], C0, 0,0,0);
    C1 = __builtin_amdgcn_mfma_f32_16x16x32_bf16(A0, B[2], C1, 0,0,0);
    C1 = __builtin_amdgcn_mfma_f32_16x16x32_bf16(A1, B[3], C1, 0,0,0);
    C2 = __builtin_amdgcn_mfma_f32_16x16x32_bf16(A0, B[4], C2, 0,0,0);
    C2 = __builtin_amdgcn_mfma_f32_16x16x32_bf16(A1, B[5], C2, 0,0,0);
    C3 = __builtin_amdgcn_mfma_f32_16x16x32_bf16(A0, B[6], C3, 0,0,0);
    C3 = __builtin_amdgcn_mfma_f32_16x16x32_bf16(A1, B[7], C3, 0,0,0);
    C4 = __builtin_amdgcn_mfma_f32_16x16x32_bf16(A0, B[8], C4, 0,0,0);
    C4 = __builtin_amdgcn_mfma_f32_16x16x32_bf16(A1, B[9], C4, 0,0,0);
    #pragma unroll
    for (int t=0;t<4;t++){
      f32x4 C = (t==0)?C0:(t==1)?C1:(t==2)?C2:C3;
      #pragma unroll
      for (int reg=0;reg<4;reg++){
        h[(rowbase + q*4 + reg)*64 + t*16 + c] = f2bf(C[reg] - cl[t]);
      }
    }
    if (c == 0){
      #pragma unroll
      for (int reg=0;reg<4;reg++) als[rowbase + q*4 + reg] = C4[reg] - const_s;
    } else if (c == 1){
      #pragma unroll
      for (int reg=0;reg<4;reg++) ald[rowbase + q*4 + reg] = C4[reg] - const_d;
    }
  }
}

// ---------------- GAT gather + precomputed-weight softmax + bias + relu + pairwise max-pool ----------------
// wave = 8 groups x 8 lanes; group g owns node 2*perm[pairslot]+(g&1).
// 3-deep software pipeline on {meta, h-row, w}. Weight read from elw (f16, streaming
// address per group, 0 on padding slots) -- the r6/r12 configuration measured at 110.5us L0
// (VALU ~84us, stall ~27us), the best gat variant of the session. UNCHANGED from r12.
__global__ __launch_bounds__(256) void gat_pool_k(const u16* __restrict__ h, const float* __restrict__ bias,
                      const int* __restrict__ indptr2, const int* __restrict__ counts,
                      const u16* __restrict__ perm, const u16* __restrict__ ell_src,
                      const _Float16* __restrict__ elw,
                      u16* __restrict__ P, int log2NS, int ecap, int nwaves)
{
  const int l = threadIdx.x & 63;
  const int g = l >> 3;
  const int o = l & 7;
  const int NB  = gridDim.x;
  const int bid = blockIdx.x;
  const int lb  = (bid & 7) * (NB >> 3) + (bid >> 3);   // XCD swizzle
  const int wv  = lb * 4 + (int)(threadIdx.x >> 6);
  if (wv >= nwaves) return;
  const int wvu = __builtin_amdgcn_readfirstlane(wv);   // wave-uniform -> SGPR-based addressing

  const int wbits = log2NS - 3;
  const int b    = wvu >> wbits;
  const int widx = wvu & ((1 << wbits) - 1);
  const int pairslot = widx*4 + (g >> 1);
  const int prow = perm[pairslot];
  const int d = 2*prow + (g & 1);
  const int nmask = (1 << log2NS) - 1;
  const int base = b << log2NS;

  const char* __restrict__ hbase  = (const char*)(h + ((size_t)base << 6));     // uniform
  const char* __restrict__ elb    = (const char*)ell_src;                       // uniform
  const char* __restrict__ wbase  = (const char*)(elw + (size_t)b * ecap);      // uniform
  const u32 olane16 = (u32)o << 4;

  const int p0  = indptr2[d];
  const int cnt = counts[d] + 1;
  const u32 moff = (u32)p0 << 1;     // byte offset: same for ell_src and elw (2B/slot)

  v2f a01={0.f,0.f}, a23={0.f,0.f}, a45={0.f,0.f}, a67={0.f,0.f};
  float z = 0.f;

  // prologue: meta for item 2; h+w for items 0,1
  u32 s0 = (u32)(*(const u16*)(elb + moff)) & nmask;
  int4 H0 = *(const int4*)(hbase + ((s0 << 7) + olane16));
  float w0f = (float)*(const _Float16*)(wbase + moff);
  u32 s1 = (u32)(*(const u16*)(elb + moff + 2)) & nmask;
  int4 H1 = *(const int4*)(hbase + ((s1 << 7) + olane16));
  float w1f = (float)*(const _Float16*)(wbase + moff + 2);
  int m2 = *(const u16*)(elb + moff + 4);

  #pragma unroll 4
  for (int it = 0; it < cnt; ++it){
    // issue h+w for item it+2
    u32 s2 = (u32)m2 & nmask;
    int4 Hn = *(const int4*)(hbase + ((s2 << 7) + olane16));
    float w2f = (float)*(const _Float16*)(wbase + (moff + ((u32)(it + 2) << 1)));
    // meta for item it+3
    int m3 = *(const u16*)(elb + (moff + ((u32)(it + 3) << 1)));
    // consume item it
    z += w0f;
    v2f w2 = {w0f, w0f};
    a01 += (v2f){ __uint_as_float(((u32)H0.x) << 16), __uint_as_float(((u32)H0.x) & 0xffff0000u) } * w2;
    a23 += (v2f){ __uint_as_float(((u32)H0.y) << 16), __uint_as_float(((u32)H0.y) & 0xffff0000u) } * w2;
    a45 += (v2f){ __uint_as_float(((u32)H0.z) << 16), __uint_as_float(((u32)H0.z) & 0xffff0000u) } * w2;
    a67 += (v2f){ __uint_as_float(((u32)H0.w) << 16), __uint_as_float(((u32)H0.w) & 0xffff0000u) } * w2;
    // shift pipeline (erased by unroll + copy-prop)
    m2 = m3;
    H0 = H1; H1 = Hn;
    w0f = w1f; w1f = w2f;
  }

  float rz = __builtin_amdgcn_rcpf(z);
  const float* bp = bias + (o << 3);          // loaded after the loop: not live across it
  float4 bA = *(const float4*)(bp);
  float4 bB = *(const float4*)(bp + 4);
  float q0 = fmaxf(fmaf(a01.x, rz, bA.x), 0.f);
  float q1 = fmaxf(fmaf(a01.y, rz, bA.y), 0.f);
  float q2 = fmaxf(fmaf(a23.x, rz, bA.z), 0.f);
  float q3 = fmaxf(fmaf(a23.y, rz, bA.w), 0.f);
  float q4 = fmaxf(fmaf(a45.x, rz, bB.x), 0.f);
  float q5 = fmaxf(fmaf(a45.y, rz, bB.y), 0.f);
  float q6 = fmaxf(fmaf(a67.x, rz, bB.z), 0.f);
  float q7 = fmaxf(fmaf(a67.y, rz, bB.w), 0.f);
  q0 = fmaxf(q0, __shfl_xor(q0, 8));
  q1 = fmaxf(q1, __shfl_xor(q1, 8));
  q2 = fmaxf(q2, __shfl_xor(q2, 8));
  q3 = fmaxf(q3, __shfl_xor(q3, 8));
  q4 = fmaxf(q4, __shfl_xor(q4, 8));
  q5 = fmaxf(q5, __shfl_xor(q5, 8));
  q6 = fmaxf(q6, __shfl_xor(q6, 8));
  q7 = fmaxf(q7, __shfl_xor(q7, 8));
  if ((g & 1) == 0){
    u32 w0 = (u32)f2bf(q0) | ((u32)f2bf(q1) << 16);
    u32 w1 = (u32)f2bf(q2) | ((u32)f2bf(q3) << 16);
    u32 w2p = (u32)f2bf(q4) | ((u32)f2bf(q5) << 16);
    u32 w3 = (u32)f2bf(q6) | ((u32)f2bf(q7) << 16);
    char* Pb = (char*)P + (((size_t)b << (log2NS - 1)) << 7);   // uniform base
    *(int4*)(Pb + (((u32)prow << 7) + olane16)) = make_int4((int)w0,(int)w1,(int)w2p,(int)w3);
  }
}

// ---------------- BatchNorm stats (stage 1) ----------------
__global__ __launch_bounds__(256) void bn_stats_k(const u16* __restrict__ P, float* __restrict__ scratch, int iters){
  const int l = threadIdx.x & 63;
  int gw = blockIdx.x*4 + (threadIdx.x>>6);
  int GW = gridDim.x*4;
  float s = 0.f, s2 = 0.f;
  #pragma unroll 4
  for (int i = 0; i < iters; i++){
    int r = gw + i*GW;
    float v = bf2f(P[(size_t)r*64 + l]);
    s += v; s2 = fmaf(v, v, s2);
  }
  __shared__ float ls[256], ls2[256];
  ls[threadIdx.x] = s; ls2[threadIdx.x] = s2;
  __syncthreads();
  if (threadIdx.x < 64){
    float S  = ls[threadIdx.x] + ls[threadIdx.x+64] + ls[threadIdx.x+128] + ls[threadIdx.x+192];
    float S2 = ls2[threadIdx.x] + ls2[threadIdx.x+64] + ls2[threadIdx.x+128] + ls2[threadIdx.x+192];
    scratch[blockIdx.x*128 + threadIdx.x] = S;
    scratch[blockIdx.x*128 + 64 + threadIdx.x] = S2;
  }
}

__global__ __launch_bounds__(128) void bn_finish_k(const float* __restrict__ scratch, float* __restrict__ stats,
                                                   int nblocks, float invN){
  __shared__ float accs[128];
  int j = threadIdx.x;
  float s = 0.f;
  #pragma unroll 8
  for (int b=0;b<nblocks;b++) s += scratch[b*128 + j];
  accs[j] = s;
  __syncthreads();
  if (j < 64){
    float m = accs[j]*invN;
    float var = accs[j+64]*invN - m*m;
    stats[j] = m;
    stats[64+j] = rsqrtf(var + BN_EPS);
  }
}

// ---------------- final BN apply: bf16 P -> f32 out ----------------
__global__ __launch_bounds__(256) void bn_apply_k(const u32* __restrict__ P2, const float* __restrict__ stats,
                                                  float4* __restrict__ out, int nq){
  int t = blockIdx.x*256 + threadIdx.x;
  if (t >= nq) return;
  int l = (t*4) & 63;
  u32 v0 = P2[t*2], v1 = P2[t*2+1];
  float4 r;
  r.x = (__uint_as_float((v0 & 0xffffu) << 16) - stats[l+0]) * stats[64+l+0];
  r.y = (__uint_as_float( v0 & 0xffff0000u    ) - stats[l+1]) * stats[64+l+1];
  r.z = (__uint_as_float((v1 & 0xffffu) << 16) - stats[l+2]) * stats[64+l+2];
  r.w = (__uint_as_float( v1 & 0xffff0000u    ) - stats[l+3]) * stats[64+l+3];
  out[t] = r;
}

// ---------------- launcher ----------------
extern "C" void kernel_launch(void* const* d_in, const int* in_sizes, int n_in,
                              void* d_out, int out_size, void* d_ws, size_t ws_size,
                              hipStream_t stream)
{
  const float* x      = (const float*)d_in[0];
  const float* Wl[3]  = {(const float*)d_in[1], (const float*)d_in[7],  (const float*)d_in[13]};
  const float* asl[3] = {(const float*)d_in[2], (const float*)d_in[8],  (const float*)d_in[14]};
  const float* adl[3] = {(const float*)d_in[3], (const float*)d_in[9],  (const float*)d_in[15]};
  const float* bl[3]  = {(const float*)d_in[4], (const float*)d_in[10], (const float*)d_in[16]};
  const int*   el[3]  = {(const int*)d_in[5],   (const int*)d_in[11],   (const int*)d_in[17]};

  const int NS[4]  = {4096, 2048, 1024, 512};
  const int EPB[3] = {32768, 16384, 8192};
  const int LOG2NS[3] = {12, 11, 10};
  const int ECAP[3] = {32768+4*4096, 16384+4*2048, 8192+4*1024};  // 49152, 24576, 12288
  const int BATCH = 256;

  char* ws = (char*)d_ws;
  size_t off = 0;
  auto alloc = [&](size_t bytes)->char*{
    char* p = ws + off; off += (bytes + 255) & ~(size_t)255; return p;
  };

  u16*   hbuf    = (u16*)alloc((size_t)BATCH*NS[0]*64*2);            // 128 MB
  u16*   Pbuf    = (u16*)alloc((size_t)BATCH*NS[1]*64*2);            //  64 MB
  float* als     = (float*)alloc((size_t)BATCH*NS[0]*4);             //   4 MB
  float* ald     = (float*)alloc((size_t)BATCH*NS[0]*4);             //   4 MB
  u16*   elw     = (u16*)alloc(((size_t)BATCH*ECAP[0] + 16)*2);      //  25.2 MB (f16 edge weights)
  float* scratch = (float*)alloc(256*128*4);
  float* stats   = (float*)alloc(128*4);
  u16*   wswz    = (u16*)alloc(10*64*8*2);
  float* cvec    = (float*)alloc(128*4);
  int* counts_all = (int*)alloc((size_t)(NS[0]+NS[1]+NS[2])*4);
  int* cursor_all = (int*)alloc((size_t)(NS[0]+NS[1]+NS[2])*4);
  int *counts[3], *cursor[3], *indptr2[3];
  u16* ell_src[3];
  u16* ell_dst[3];
  u16* perm[3];
  counts[0]=counts_all; counts[1]=counts_all+NS[0]; counts[2]=counts_all+NS[0]+NS[1];
  cursor[0]=cursor_all; cursor[1]=cursor_all+NS[0]; cursor[2]=cursor_all+NS[0]+NS[1];
  for (int i=0;i<3;i++){
    indptr2[i] = (int*)alloc((size_t)(NS[i]+1)*4);
    ell_src[i] = (u16*)alloc((size_t)(ECAP[i]+16)*2);
    ell_dst[i] = (u16*)alloc((size_t)(ECAP[i]+16)*2);
    perm[i]    = (u16*)alloc((size_t)NS[i]);      // NS/2 pairs * 2B
  }
  if (off > ws_size) return;

  // ---- build ----
  int ctot = NS[0]+NS[1]+NS[2];
  {
    dim3 ginit((ECAP[0]+16+255)/256, 4);
    init_k<<<ginit, 256, 0, stream>>>(counts_all, ell_src[0], ell_src[1], ell_src[2],
                                      ctot, ECAP[0]+16, ECAP[1]+16, ECAP[2]+16);
    dim3 ghist(EPB[0]/256, 3);
    hist_all_k<<<ghist, 256, 0, stream>>>(el[0], el[1], el[2], counts[0], counts[1], counts[2],
                                          EPB[0], EPB[1], EPB[2]);
    scan_all_k<<<3, 1024, 0, stream>>>(counts[0], counts[1], counts[2],
                                       indptr2[0], indptr2[1], indptr2[2],
                                       cursor[0], cursor[1], cursor[2],
                                       ell_src[0], ell_src[1], ell_src[2],
                                       ell_dst[0], ell_dst[1], ell_dst[2],
                                       NS[0], NS[1], NS[2]);
    scatter_all_k<<<ghist, 256, 0, stream>>>(el[0], el[1], el[2],
                                             cursor[0], cursor[1], cursor[2],
                                             ell_src[0], ell_src[1], ell_src[2],
                                             ell_dst[0], ell_dst[1], ell_dst[2],
                                             EPB[0], EPB[1], EPB[2]);
    pairsort_k<<<3, 1024, 0, stream>>>(counts[0], counts[1], counts[2],
                                       perm[0], perm[1], perm[2],
                                       NS[0]/2, NS[1]/2, NS[2]/2);
  }

  // ---- layers ----
  for (int i=0;i<3;i++){
    int ntot = BATCH*NS[i];

    if (i==0){
      gemm3_k<<<1024, 256, 0, stream>>>(x, Wl[0], asl[0], adl[0], hbuf, als, ald, ntot/8);
    } else {
      float invN = 1.0f / (float)(BATCH*NS[i]);   // prev pooled rows = BATCH*NS[i-1]/2 = BATCH*NS[i]
      prep_w_k<<<1, 128, 0, stream>>>(Wl[i], asl[i], adl[i], scratch, invN, wswz, cvec);
      gemm64_mfma_k<<<2048, 256, 0, stream>>>(Pbuf, wswz, cvec, hbuf, als, ald, ntot/16);
    }

    // edge-softmax weights: LDS-staged, 4 blocks/graph (full occupancy)
    weight_lds_k<<<dim3(4, BATCH), 512, 0, stream>>>(ell_src[i], ell_dst[i], als, ald,
                                                     (_Float16*)elw, LOG2NS[i], ECAP[i]);

    int nwaves = ntot/8;
    gat_pool_k<<<nwaves/4, 256, 0, stream>>>(hbuf, bl[i], indptr2[i], counts[i], perm[i],
                                             ell_src[i], (const _Float16*)elw,
                                             Pbuf, LOG2NS[i], ECAP[i], nwaves);

    bn_stats_k<<<256, 256, 0, stream>>>(Pbuf, scratch, (ntot/2)/1024);
  }

  // final BN: finish stats of layer 2, then materialize into d_out
  bn_finish_k<<<1, 128, 0, stream>>>(scratch, stats, 256, 1.0f/(float)(BATCH*NS[3]));
  int nq = out_size/4;
  bn_apply_k<<<(nq+255)/256, 256, 0, stream>>>((const u32*)Pbuf, stats, (float4*)d_out, nq);
}

// Round 16
// 537.711 us; speedup vs baseline: 1.0679x; 1.0346x over previous
//
#include <hip/hip_runtime.h>
#include <stdint.h>

#define NEG_SLOPE 0.2f
#define BN_EPS 1e-5f
#define LOG2E 1.4426950408889634f

typedef unsigned short u16;
typedef unsigned int   u32;
typedef __attribute__((ext_vector_type(2))) float  v2f;
typedef __attribute__((ext_vector_type(4))) float  f32x4;
typedef __attribute__((ext_vector_type(8))) short  short8;

__device__ __forceinline__ float bf2f(u16 u){ return __uint_as_float(((u32)u) << 16); }
__device__ __forceinline__ u16 f2bf(float f){           // round-to-nearest-even
  u32 u = __float_as_uint(f);
  return (u16)((u + 0x7fffu + ((u >> 16) & 1u)) >> 16);
}

// ---------------- build phase ----------------
// y=0: zero counts; y=1..3: fill ell_src[L] with 0xFFFF
__global__ __launch_bounds__(256) void init_k(int* __restrict__ counts, u16* __restrict__ s0,
                                              u16* __restrict__ s1, u16* __restrict__ s2,
                                              int nc, int n0, int n1, int n2){
  int t = blockIdx.x*256 + threadIdx.x;
  int y = blockIdx.y;
  if (y==0){ if (t<nc) counts[t]=0; }
  else {
    u16* sd = (y==1)?s0:(y==2)?s1:s2;
    int n   = (y==1)?n0:(y==2)?n1:n2;
    if (t<n) sd[t]=0xFFFFu;
  }
}

__global__ __launch_bounds__(256) void hist_all_k(const int* __restrict__ el0, const int* __restrict__ el1,
                                                  const int* __restrict__ el2, int* __restrict__ c0,
                                                  int* __restrict__ c1, int* __restrict__ c2,
                                                  int n0, int n1, int n2){
  int t = blockIdx.x*256 + threadIdx.x;
  int L = blockIdx.y;
  const int* dst = (L==0)?(el0+n0):(L==1)?(el1+n1):(el2+n2);
  int* counts    = (L==0)?c0:(L==1)?c1:c2;
  int n          = (L==0)?n0:(L==1)?n1:n2;
  if (t < n) atomicAdd(&counts[dst[t]], 1);
}

// padded scan per layer: row len = (deg+4)&~3 (>= deg+1), self at slot 0
__global__ __launch_bounds__(1024) void scan_all_k(int* __restrict__ c0, int* __restrict__ c1, int* __restrict__ c2,
                         int* __restrict__ ip0, int* __restrict__ ip1, int* __restrict__ ip2,
                         int* __restrict__ cu0, int* __restrict__ cu1, int* __restrict__ cu2,
                         u16* __restrict__ sd0, u16* __restrict__ sd1, u16* __restrict__ sd2,
                         int n0, int n1, int n2){
  int L = blockIdx.x;
  const int* counts = (L==0)?c0:(L==1)?c1:c2;
  int* indptr2      = (L==0)?ip0:(L==1)?ip1:ip2;
  int* cursor       = (L==0)?cu0:(L==1)?cu1:cu2;
  u16* ell_src      = (L==0)?sd0:(L==1)?sd1:sd2;
  int n             = (L==0)?n0:(L==1)?n1:n2;
  __shared__ int part[1024];
  int tid = threadIdx.x;
  int base = tid*4;
  int v0=0,v1=0,v2=0,v3=0;
  if (base+0<n) v0 = (counts[base+0]+4)&~3;
  if (base+1<n) v1 = (counts[base+1]+4)&~3;
  if (base+2<n) v2 = (counts[base+2]+4)&~3;
  if (base+3<n) v3 = (counts[base+3]+4)&~3;
  part[tid] = v0+v1+v2+v3;
  __syncthreads();
  for (int off=1; off<1024; off<<=1){
    int t2 = (tid>=off)?part[tid-off]:0;
    __syncthreads();
    part[tid] += t2;
    __syncthreads();
  }
  int run = (tid>0)?part[tid-1]:0;
  if (base+0<n){ indptr2[base+0]=run; cursor[base+0]=run+1; ell_src[run]=(u16)(base+0); run+=v0; }
  if (base+1<n){ indptr2[base+1]=run; cursor[base+1]=run+1; ell_src[run]=(u16)(base+1); run+=v1; }
  if (base+2<n){ indptr2[base+2]=run; cursor[base+2]=run+1; ell_src[run]=(u16)(base+2); run+=v2; }
  if (base+3<n){ indptr2[base+3]=run; cursor[base+3]=run+1; ell_src[run]=(u16)(base+3); run+=v3; }
  if (tid==0) indptr2[n] = part[1023];
}

__global__ __launch_bounds__(256) void scatter_all_k(const int* __restrict__ el0, const int* __restrict__ el1,
                         const int* __restrict__ el2, int* __restrict__ cu0, int* __restrict__ cu1,
                         int* __restrict__ cu2, u16* __restrict__ sd0, u16* __restrict__ sd1,
                         u16* __restrict__ sd2, int n0, int n1, int n2){
  int t = blockIdx.x*256 + threadIdx.x;
  int L = blockIdx.y;
  const int* el = (L==0)?el0:(L==1)?el1:el2;
  int* cursor   = (L==0)?cu0:(L==1)?cu1:cu2;
  u16* ell_src  = (L==0)?sd0:(L==1)?sd1:sd2;
  int n         = (L==0)?n0:(L==1)?n1:n2;
  if (t < n){
    int dd = el[n + t];
    int p = atomicAdd(&cursor[dd], 1);
    ell_src[p] = (u16)el[t];
  }
}

// counting sort of pool-pairs by max(deg) -> perm (shared by all graphs)
__global__ __launch_bounds__(1024) void pairsort_k(const int* __restrict__ c0, const int* __restrict__ c1,
                         const int* __restrict__ c2, u16* __restrict__ pm0, u16* __restrict__ pm1,
                         u16* __restrict__ pm2, int np0, int np1, int np2){
  int L = blockIdx.x;
  const int* counts = (L==0)?c0:(L==1)?c1:c2;
  u16* perm = (L==0)?pm0:(L==1)?pm1:pm2;
  int np    = (L==0)?np0:(L==1)?np1:np2;
  __shared__ int hist[64];
  __shared__ int pos[64];
  int t = threadIdx.x;
  if (t < 64) hist[t] = 0;
  __syncthreads();
  for (int p=t; p<np; p+=1024){
    int k = min(max(counts[2*p], counts[2*p+1]), 63);
    atomicAdd(&hist[k], 1);
  }
  __syncthreads();
  if (t == 0){ int run=0; for (int i=0;i<64;i++){ pos[i]=run; run+=hist[i]; } }
  __syncthreads();
  for (int p=t; p<np; p+=1024){
    int k = min(max(counts[2*p], counts[2*p+1]), 63);
    int q = atomicAdd(&pos[k], 1);
    perm[q] = (u16)p;
  }
}

// ---------------- layer-0 GEMM: x[n,3] @ W0[3,64] -> h bf16, LOG2E-prescaled al_s/al_d ----------------
__global__ __launch_bounds__(256) void gemm3_k(const float* __restrict__ x, const float* __restrict__ Wg,
                        const float* __restrict__ asrc, const float* __restrict__ adst,
                        u16* __restrict__ h, float* __restrict__ als, float* __restrict__ ald, int nrows8)
{
  const int l = threadIdx.x & 63;
  const int g = l >> 3;
  const int o = l & 7;
  float W0[8], W1[8], W2[8];
  float vs0=0.f,vs1=0.f,vs2=0.f,vd0=0.f,vd1=0.f,vd2=0.f;
  #pragma unroll
  for (int j=0;j<8;j++){
    W0[j] = Wg[      o*8 + j];
    W1[j] = Wg[ 64 + o*8 + j];
    W2[j] = Wg[128 + o*8 + j];
    float as = asrc[o*8 + j], ad = adst[o*8 + j];
    vs0 = fmaf(W0[j], as, vs0); vs1 = fmaf(W1[j], as, vs1); vs2 = fmaf(W2[j], as, vs2);
    vd0 = fmaf(W0[j], ad, vd0); vd1 = fmaf(W1[j], ad, vd1); vd2 = fmaf(W2[j], ad, vd2);
  }
  #pragma unroll
  for (int off=1; off<8; off<<=1){
    vs0 += __shfl_xor(vs0,off); vs1 += __shfl_xor(vs1,off); vs2 += __shfl_xor(vs2,off);
    vd0 += __shfl_xor(vd0,off); vd1 += __shfl_xor(vd1,off); vd2 += __shfl_xor(vd2,off);
  }
  int wv = blockIdx.x*4 + (int)(threadIdx.x>>6);
  int stride = gridDim.x*4;
  for (int blk = wv; blk < nrows8; blk += stride){
    int r = blk*8 + g;
    float x0 = x[(size_t)r*3+0];
    float x1 = x[(size_t)r*3+1];
    float x2 = x[(size_t)r*3+2];
    u32 pk[4];
    #pragma unroll
    for (int j=0;j<8;j+=2){
      float a0 = fmaf(x0, W0[j],   fmaf(x1, W1[j],   x2*W2[j]));
      float a1 = fmaf(x0, W0[j+1], fmaf(x1, W1[j+1], x2*W2[j+1]));
      pk[j>>1] = (u32)f2bf(a0) | ((u32)f2bf(a1) << 16);
    }
    ((int4*)(h + ((size_t)r << 6)))[o] = make_int4((int)pk[0],(int)pk[1],(int)pk[2],(int)pk[3]);
    if (o == 0){
      als[r] = LOG2E * fmaf(x2, vs2, fmaf(x1, vs1, x0*vs0));
      ald[r] = LOG2E * fmaf(x2, vd2, fmaf(x1, vd1, x0*vd0));
    }
  }
}

// ---------------- prep (layers 1/2): BN finish of prev layer + W' frags + als/ald B-tile ----------------
__global__ __launch_bounds__(128) void prep_w_k(const float* __restrict__ W, const float* __restrict__ asrc,
                        const float* __restrict__ adst, const float* __restrict__ scratch, float invN,
                        u16* __restrict__ wswz, float* __restrict__ cvec){
  __shared__ float mean_s[64], rstd_s[64], vs_s[64], vd_s[64], cv_s[64], acc[128];
  int t = threadIdx.x;
  float s = 0.f;
  #pragma unroll 8
  for (int b2=0;b2<256;b2++) s += scratch[b2*128 + t];
  acc[t] = s;
  __syncthreads();
  if (t < 64){
    float m = acc[t]*invN;
    float var = acc[64+t]*invN - m*m;
    mean_s[t] = m; rstd_s[t] = rsqrtf(var + BN_EPS);
  }
  __syncthreads();
  if (t < 64){
    float c = 0.f;
    for (int k=0;k<64;k++) c = fmaf(mean_s[k]*rstd_s[k], W[k*64+t], c);
    cv_s[t] = c; cvec[t] = c;
    float vs = 0.f, vd = 0.f;
    for (int col=0; col<64; col++){
      float wv = W[t*64+col];
      vs = fmaf(wv, asrc[col], vs);
      vd = fmaf(wv, adst[col], vd);
    }
    vs_s[t] = rstd_s[t]*vs; vd_s[t] = rstd_s[t]*vd;
  }
  __syncthreads();
  if (t == 0){
    float cs=0.f, cd=0.f;
    for (int col=0; col<64; col++){ cs = fmaf(cv_s[col], asrc[col], cs); cd = fmaf(cv_s[col], adst[col], cd); }
    cvec[64] = cs; cvec[65] = cd;
  }
  if (t < 64){
    #pragma unroll
    for (int f=0; f<8; f++){
      int tt = f >> 1, ch = f & 1;
      #pragma unroll
      for (int j=0; j<8; j++){
        int k   = ch*32 + (t>>4)*8 + j;
        int col = tt*16 + (t&15);
        wswz[(f*64 + t)*8 + j] = f2bf(rstd_s[k] * W[k*64 + col]);
      }
    }
    #pragma unroll
    for (int f=8; f<10; f++){
      int ch = f - 8;
      #pragma unroll
      for (int j=0; j<8; j++){
        int k = ch*32 + (t>>4)*8 + j;
        int colp = t & 15;
        float val = (colp==0)? vs_s[k] : (colp==1)? vd_s[k] : 0.f;
        wswz[(f*64 + t)*8 + j] = f2bf(val);
      }
    }
  }
}

// ---------------- layers 1/2 GEMM via MFMA: h = P @ W' - c; LOG2E-prescaled als/ald ----------------
__global__ __launch_bounds__(256) void gemm64_mfma_k(const u16* __restrict__ Pin, const u16* __restrict__ wswz,
                        const float* __restrict__ cvec,
                        u16* __restrict__ h, float* __restrict__ als, float* __restrict__ ald, int nblk16)
{
  const int l = threadIdx.x & 63;
  const int q = l >> 4;
  const int c = l & 15;
  short8 B[10];
  const int4* wsw = (const int4*)wswz;
  #pragma unroll
  for (int f=0; f<10; f++){
    int4 v = wsw[f*64 + l];
    B[f] = *(short8*)&v;
  }
  float cl[4];
  #pragma unroll
  for (int t=0;t<4;t++) cl[t] = cvec[t*16+c];
  const float const_s = cvec[64], const_d = cvec[65];
  int gw = blockIdx.x*4 + (int)(threadIdx.x>>6);
  int stride = gridDim.x*4;
  for (int blk = gw; blk < nblk16; blk += stride){
    size_t rowbase = (size_t)blk*16;
    const int4* arow = (const int4*)(Pin + (rowbase + c)*64);
    int4 a0v = arow[q];
    int4 a1v = arow[4+q];
    short8 A0 = *(short8*)&a0v, A1 = *(short8*)&a1v;
    f32x4 C0={0.f,0.f,0.f,0.f}, C1=C0, C2=C0, C3=C0, C4=C0;
    C0 = __builtin_amdgcn_mfma_f32_16x16x32_bf16(A0, B[0], C0, 0,0,0);
    C0 = __builtin_amdgcn_mfma_f32_16x16x32_bf16(A1, B[1], C0, 0,0,0);
    C1 = __builtin_amdgcn_mfma_f32_16x16x32_bf16(A0, B[2], C1, 0,0,0);
    C1 = __builtin_amdgcn_mfma_f32_16x16x32_bf16(A1, B[3], C1, 0,0,0);
    C2 = __builtin_amdgcn_mfma_f32_16x16x32_bf16(A0, B[4], C2, 0,0,0);
    C2 = __builtin_amdgcn_mfma_f32_16x16x32_bf16(A1, B[5], C2, 0,0,0);
    C3 = __builtin_amdgcn_mfma_f32_16x16x32_bf16(A0, B[6], C3, 0,0,0);
    C3 = __builtin_amdgcn_mfma_f32_16x16x32_bf16(A1, B[7], C3, 0,0,0);
    C4 = __builtin_amdgcn_mfma_f32_16x16x32_bf16(A0, B[8], C4, 0,0,0);
    C4 = __builtin_amdgcn_mfma_f32_16x16x32_bf16(A1, B[9], C4, 0,0,0);
    #pragma unroll
    for (int t=0;t<4;t++){
      f32x4 C = (t==0)?C0:(t==1)?C1:(t==2)?C2:C3;
      #pragma unroll
      for (int reg=0;reg<4;reg++){
        h[(rowbase + q*4 + reg)*64 + t*16 + c] = f2bf(C[reg] - cl[t]);
      }
    }
    if (c == 0){
      #pragma unroll
      for (int reg=0;reg<4;reg++) als[rowbase + q*4 + reg] = (C4[reg] - const_s) * LOG2E;
    } else if (c == 1){
      #pragma unroll
      for (int reg=0;reg<4;reg++) ald[rowbase + q*4 + reg] = (C4[reg] - const_d) * LOG2E;
    }
  }
}

// ---------------- GAT gather + inline edge-softmax + bias + relu + pairwise max-pool ----------------
// r4 structure (session best, 126.5us L0): readfirstlane SGPR bases, int4 h-row loads,
// 2-ahead pipeline, unroll 4. Two calibrated slot removals vs r4:
//  (1) dead padding-mask dropped (loop consumes exactly cnt real slots; padding only prefetched)
//      -> m0/m1 no longer carried, only prefetch meta m2/m3.
//  (2) als/ald prescaled by LOG2E at producers -> w = exp2(max(t,0.2t)), no in-loop mul.
__global__ __launch_bounds__(256) void gat_pool_k(const u16* __restrict__ h, const float* __restrict__ bias,
                      const int* __restrict__ indptr2, const int* __restrict__ counts,
                      const u16* __restrict__ perm, const u16* __restrict__ ell_src,
                      const float* __restrict__ als, const float* __restrict__ ald,
                      u16* __restrict__ P, int log2NS, int nwaves)
{
  const int l = threadIdx.x & 63;
  const int g = l >> 3;
  const int o = l & 7;
  const int NB  = gridDim.x;
  const int bid = blockIdx.x;
  const int lb  = (bid & 7) * (NB >> 3) + (bid >> 3);   // XCD swizzle
  const int wv  = lb * 4 + (int)(threadIdx.x >> 6);
  if (wv >= nwaves) return;
  const int wvu = __builtin_amdgcn_readfirstlane(wv);   // wave-uniform -> SGPR-based addressing

  const int wbits = log2NS - 3;
  const int b    = wvu >> wbits;
  const int widx = wvu & ((1 << wbits) - 1);
  const int pairslot = widx*4 + (g >> 1);
  const int prow = perm[pairslot];
  const int d = 2*prow + (g & 1);
  const int nmask = (1 << log2NS) - 1;
  const int base = b << log2NS;

  const char* __restrict__ hbase  = (const char*)(h + ((size_t)base << 6));   // uniform
  const char* __restrict__ albase = (const char*)(als + base);                // uniform
  const char* __restrict__ elb    = (const char*)ell_src;                     // uniform
  const u32 olane16 = (u32)o << 4;

  const int p0  = indptr2[d];
  const int cnt = counts[d] + 1;
  const float ald_d = ald[base + d];
  const u32 moff = (u32)p0 << 1;

  v2f a01={0.f,0.f}, a23={0.f,0.f}, a45={0.f,0.f}, a67={0.f,0.f};
  float z = 0.f;

  // prologue: h+als for items 0,1; prefetch meta for item 2
  u32 s0 = (u32)(*(const u16*)(elb + moff)) & nmask;
  int4 H0 = *(const int4*)(hbase + ((s0 << 7) + olane16));
  float al0 = *(const float*)(albase + (s0 << 2));
  u32 s1 = (u32)(*(const u16*)(elb + moff + 2)) & nmask;
  int4 H1 = *(const int4*)(hbase + ((s1 << 7) + olane16));
  float al1 = *(const float*)(albase + (s1 << 2));
  int m2 = *(const u16*)(elb + moff + 4);

  #pragma unroll 4
  for (int it = 0; it < cnt; ++it){
    // issue h+als for item it+2 (meta m2)
    u32 s2 = (u32)m2 & nmask;
    int4 Hn = *(const int4*)(hbase + ((s2 << 7) + olane16));
    float al2 = *(const float*)(albase + (s2 << 2));
    // meta for item it+3
    int m3 = *(const u16*)(elb + (moff + ((u32)(it + 3) << 1)));
    // consume item it: w = exp2(max(t, 0.2t))  [als/ald prescaled by LOG2E; no mask]
    float t = al0 + ald_d;
    float w = exp2f(fmaxf(t, NEG_SLOPE*t));
    z += w;
    v2f w2 = {w, w};
    a01 += (v2f){ __uint_as_float(((u32)H0.x) << 16), __uint_as_float(((u32)H0.x) & 0xffff0000u) } * w2;
    a23 += (v2f){ __uint_as_float(((u32)H0.y) << 16), __uint_as_float(((u32)H0.y) & 0xffff0000u) } * w2;
    a45 += (v2f){ __uint_as_float(((u32)H0.z) << 16), __uint_as_float(((u32)H0.z) & 0xffff0000u) } * w2;
    a67 += (v2f){ __uint_as_float(((u32)H0.w) << 16), __uint_as_float(((u32)H0.w) & 0xffff0000u) } * w2;
    // shift pipeline (erased by unroll + copy-prop)
    m2 = m3;
    H0 = H1; al0 = al1;
    H1 = Hn; al1 = al2;
  }

  float rz = __builtin_amdgcn_rcpf(z);
  const float* bp = bias + (o << 3);          // loaded after the loop: not live across it
  float4 bA = *(const float4*)(bp);
  float4 bB = *(const float4*)(bp + 4);
  float q0 = fmaxf(fmaf(a01.x, rz, bA.x), 0.f);
  float q1 = fmaxf(fmaf(a01.y, rz, bA.y), 0.f);
  float q2 = fmaxf(fmaf(a23.x, rz, bA.z), 0.f);
  float q3 = fmaxf(fmaf(a23.y, rz, bA.w), 0.f);
  float q4 = fmaxf(fmaf(a45.x, rz, bB.x), 0.f);
  float q5 = fmaxf(fmaf(a45.y, rz, bB.y), 0.f);
  float q6 = fmaxf(fmaf(a67.x, rz, bB.z), 0.f);
  float q7 = fmaxf(fmaf(a67.y, rz, bB.w), 0.f);
  q0 = fmaxf(q0, __shfl_xor(q0, 8));
  q1 = fmaxf(q1, __shfl_xor(q1, 8));
  q2 = fmaxf(q2, __shfl_xor(q2, 8));
  q3 = fmaxf(q3, __shfl_xor(q3, 8));
  q4 = fmaxf(q4, __shfl_xor(q4, 8));
  q5 = fmaxf(q5, __shfl_xor(q5, 8));
  q6 = fmaxf(q6, __shfl_xor(q6, 8));
  q7 = fmaxf(q7, __shfl_xor(q7, 8));
  if ((g & 1) == 0){
    u32 w0 = (u32)f2bf(q0) | ((u32)f2bf(q1) << 16);
    u32 w1 = (u32)f2bf(q2) | ((u32)f2bf(q3) << 16);
    u32 w2p = (u32)f2bf(q4) | ((u32)f2bf(q5) << 16);
    u32 w3 = (u32)f2bf(q6) | ((u32)f2bf(q7) << 16);
    char* Pb = (char*)P + (((size_t)b << (log2NS - 1)) << 7);   // uniform base
    *(int4*)(Pb + (((u32)prow << 7) + olane16)) = make_int4((int)w0,(int)w1,(int)w2p,(int)w3);
  }
}

// ---------------- BatchNorm stats (stage 1) ----------------
__global__ __launch_bounds__(256) void bn_stats_k(const u16* __restrict__ P, float* __restrict__ scratch, int iters){
  const int l = threadIdx.x & 63;
  int gw = blockIdx.x*4 + (threadIdx.x>>6);
  int GW = gridDim.x*4;
  float s = 0.f, s2 = 0.f;
  #pragma unroll 4
  for (int i = 0; i < iters; i++){
    int r = gw + i*GW;
    float v = bf2f(P[(size_t)r*64 + l]);
    s += v; s2 = fmaf(v, v, s2);
  }
  __shared__ float ls[256], ls2[256];
  ls[threadIdx.x] = s; ls2[threadIdx.x] = s2;
  __syncthreads();
  if (threadIdx.x < 64){
    float S  = ls[threadIdx.x] + ls[threadIdx.x+64] + ls[threadIdx.x+128] + ls[threadIdx.x+192];
    float S2 = ls2[threadIdx.x] + ls2[threadIdx.x+64] + ls2[threadIdx.x+128] + ls2[threadIdx.x+192];
    scratch[blockIdx.x*128 + threadIdx.x] = S;
    scratch[blockIdx.x*128 + 64 + threadIdx.x] = S2;
  }
}

__global__ __launch_bounds__(128) void bn_finish_k(const float* __restrict__ scratch, float* __restrict__ stats,
                                                   int nblocks, float invN){
  __shared__ float accs[128];
  int j = threadIdx.x;
  float s = 0.f;
  #pragma unroll 8
  for (int b=0;b<nblocks;b++) s += scratch[b*128 + j];
  accs[j] = s;
  __syncthreads();
  if (j < 64){
    float m = accs[j]*invN;
    float var = accs[j+64]*invN - m*m;
    stats[j] = m;
    stats[64+j] = rsqrtf(var + BN_EPS);
  }
}

// ---------------- final BN apply: bf16 P -> f32 out ----------------
__global__ __launch_bounds__(256) void bn_apply_k(const u32* __restrict__ P2, const float* __restrict__ stats,
                                                  float4* __restrict__ out, int nq){
  int t = blockIdx.x*256 + threadIdx.x;
  if (t >= nq) return;
  int l = (t*4) & 63;
  u32 v0 = P2[t*2], v1 = P2[t*2+1];
  float4 r;
  r.x = (__uint_as_float((v0 & 0xffffu) << 16) - stats[l+0]) * stats[64+l+0];
  r.y = (__uint_as_float( v0 & 0xffff0000u    ) - stats[l+1]) * stats[64+l+1];
  r.z = (__uint_as_float((v1 & 0xffffu) << 16) - stats[l+2]) * stats[64+l+2];
  r.w = (__uint_as_float( v1 & 0xffff0000u    ) - stats[l+3]) * stats[64+l+3];
  out[t] = r;
}

// ---------------- launcher ----------------
extern "C" void kernel_launch(void* const* d_in, const int* in_sizes, int n_in,
                              void* d_out, int out_size, void* d_ws, size_t ws_size,
                              hipStream_t stream)
{
  const float* x      = (const float*)d_in[0];
  const float* Wl[3]  = {(const float*)d_in[1], (const float*)d_in[7],  (const float*)d_in[13]};
  const float* asl[3] = {(const float*)d_in[2], (const float*)d_in[8],  (const float*)d_in[14]};
  const float* adl[3] = {(const float*)d_in[3], (const float*)d_in[9],  (const float*)d_in[15]};
  const float* bl[3]  = {(const float*)d_in[4], (const float*)d_in[10], (const float*)d_in[16]};
  const int*   el[3]  = {(const int*)d_in[5],   (const int*)d_in[11],   (const int*)d_in[17]};

  const int NS[4]  = {4096, 2048, 1024, 512};
  const int EPB[3] = {32768, 16384, 8192};
  const int LOG2NS[3] = {12, 11, 10};
  const int ECAP[3] = {32768+4*4096, 16384+4*2048, 8192+4*1024};  // 49152, 24576, 12288
  const int BATCH = 256;

  char* ws = (char*)d_ws;
  size_t off = 0;
  auto alloc = [&](size_t bytes)->char*{
    char* p = ws + off; off += (bytes + 255) & ~(size_t)255; return p;
  };

  u16*   hbuf    = (u16*)alloc((size_t)BATCH*NS[0]*64*2);            // 128 MB
  u16*   Pbuf    = (u16*)alloc((size_t)BATCH*NS[1]*64*2);            //  64 MB
  float* als     = (float*)alloc((size_t)BATCH*NS[0]*4);             //   4 MB
  float* ald     = (float*)alloc((size_t)BATCH*NS[0]*4);             //   4 MB
  float* scratch = (float*)alloc(256*128*4);
  float* stats   = (float*)alloc(128*4);
  u16*   wswz    = (u16*)alloc(10*64*8*2);
  float* cvec    = (float*)alloc(128*4);
  int* counts_all = (int*)alloc((size_t)(NS[0]+NS[1]+NS[2])*4);
  int* cursor_all = (int*)alloc((size_t)(NS[0]+NS[1]+NS[2])*4);
  int *counts[3], *cursor[3], *indptr2[3];
  u16* ell_src[3];
  u16* perm[3];
  counts[0]=counts_all; counts[1]=counts_all+NS[0]; counts[2]=counts_all+NS[0]+NS[1];
  cursor[0]=cursor_all; cursor[1]=cursor_all+NS[0]; cursor[2]=cursor_all+NS[0]+NS[1];
  for (int i=0;i<3;i++){
    indptr2[i] = (int*)alloc((size_t)(NS[i]+1)*4);
    ell_src[i] = (u16*)alloc((size_t)(ECAP[i]+16)*2);
    perm[i]    = (u16*)alloc((size_t)NS[i]);      // NS/2 pairs * 2B
  }
  if (off > ws_size) return;

  // ---- build ----
  int ctot = NS[0]+NS[1]+NS[2];
  {
    dim3 ginit((ECAP[0]+16+255)/256, 4);
    init_k<<<ginit, 256, 0, stream>>>(counts_all, ell_src[0], ell_src[1], ell_src[2],
                                      ctot, ECAP[0]+16, ECAP[1]+16, ECAP[2]+16);
    dim3 ghist(EPB[0]/256, 3);
    hist_all_k<<<ghist, 256, 0, stream>>>(el[0], el[1], el[2], counts[0], counts[1], counts[2],
                                          EPB[0], EPB[1], EPB[2]);
    scan_all_k<<<3, 1024, 0, stream>>>(counts[0], counts[1], counts[2],
                                       indptr2[0], indptr2[1], indptr2[2],
                                       cursor[0], cursor[1], cursor[2],
                                       ell_src[0], ell_src[1], ell_src[2],
                                       NS[0], NS[1], NS[2]);
    scatter_all_k<<<ghist, 256, 0, stream>>>(el[0], el[1], el[2],
                                             cursor[0], cursor[1], cursor[2],
                                             ell_src[0], ell_src[1], ell_src[2],
                                             EPB[0], EPB[1], EPB[2]);
    pairsort_k<<<3, 1024, 0, stream>>>(counts[0], counts[1], counts[2],
                                       perm[0], perm[1], perm[2],
                                       NS[0]/2, NS[1]/2, NS[2]/2);
  }

  // ---- layers ----
  for (int i=0;i<3;i++){
    int ntot = BATCH*NS[i];

    if (i==0){
      gemm3_k<<<1024, 256, 0, stream>>>(x, Wl[0], asl[0], adl[0], hbuf, als, ald, ntot/8);
    } else {
      float invN = 1.0f / (float)(BATCH*NS[i]);   // prev pooled rows = BATCH*NS[i-1]/2 = BATCH*NS[i]
      prep_w_k<<<1, 128, 0, stream>>>(Wl[i], asl[i], adl[i], scratch, invN, wswz, cvec);
      gemm64_mfma_k<<<2048, 256, 0, stream>>>(Pbuf, wswz, cvec, hbuf, als, ald, ntot/16);
    }

    int nwaves = ntot/8;
    gat_pool_k<<<nwaves/4, 256, 0, stream>>>(hbuf, bl[i], indptr2[i], counts[i], perm[i],
                                             ell_src[i], als, ald,
                                             Pbuf, LOG2NS[i], nwaves);

    bn_stats_k<<<256, 256, 0, stream>>>(Pbuf, scratch, (ntot/2)/1024);
  }

  // final BN: finish stats of layer 2, then materialize into d_out
  bn_finish_k<<<1, 128, 0, stream>>>(scratch, stats, 256, 1.0f/(float)(BATCH*NS[3]));
  int nq = out_size/4;
  bn_apply_k<<<(nq+255)/256, 256, 0, stream>>>((const u32*)Pbuf, stats, (float4*)d_out, nq);
}

// Round 17
// 521.548 us; speedup vs baseline: 1.1010x; 1.0310x over previous
//
#include <hip/hip_runtime.h>
#include <stdint.h>

#define NEG_SLOPE 0.2f
#define BN_EPS 1e-5f
#define LOG2E 1.4426950408889634f

typedef unsigned short u16;
typedef unsigned int   u32;
typedef __attribute__((ext_vector_type(2))) float  v2f;
typedef __attribute__((ext_vector_type(4))) float  f32x4;
typedef __attribute__((ext_vector_type(8))) short  short8;

__device__ __forceinline__ float bf2f(u16 u){ return __uint_as_float(((u32)u) << 16); }
__device__ __forceinline__ u16 f2bf(float f){           // round-to-nearest-even
  u32 u = __float_as_uint(f);
  return (u16)((u + 0x7fffu + ((u >> 16) & 1u)) >> 16);
}

// ---------------- build phase ----------------
// y=0: zero counts; y=1..3: fill ell_src[L] with 0xFFFF
__global__ __launch_bounds__(256) void init_k(int* __restrict__ counts, u16* __restrict__ s0,
                                              u16* __restrict__ s1, u16* __restrict__ s2,
                                              int nc, int n0, int n1, int n2){
  int t = blockIdx.x*256 + threadIdx.x;
  int y = blockIdx.y;
  if (y==0){ if (t<nc) counts[t]=0; }
  else {
    u16* sd = (y==1)?s0:(y==2)?s1:s2;
    int n   = (y==1)?n0:(y==2)?n1:n2;
    if (t<n) sd[t]=0xFFFFu;
  }
}

__global__ __launch_bounds__(256) void hist_all_k(const int* __restrict__ el0, const int* __restrict__ el1,
                                                  const int* __restrict__ el2, int* __restrict__ c0,
                                                  int* __restrict__ c1, int* __restrict__ c2,
                                                  int n0, int n1, int n2){
  int t = blockIdx.x*256 + threadIdx.x;
  int L = blockIdx.y;
  const int* dst = (L==0)?(el0+n0):(L==1)?(el1+n1):(el2+n2);
  int* counts    = (L==0)?c0:(L==1)?c1:c2;
  int n          = (L==0)?n0:(L==1)?n1:n2;
  if (t < n) atomicAdd(&counts[dst[t]], 1);
}

// padded scan per layer: row len = (deg+4)&~3 (>= deg+1), self at slot 0
__global__ __launch_bounds__(1024) void scan_all_k(int* __restrict__ c0, int* __restrict__ c1, int* __restrict__ c2,
                         int* __restrict__ ip0, int* __restrict__ ip1, int* __restrict__ ip2,
                         int* __restrict__ cu0, int* __restrict__ cu1, int* __restrict__ cu2,
                         u16* __restrict__ sd0, u16* __restrict__ sd1, u16* __restrict__ sd2,
                         int n0, int n1, int n2){
  int L = blockIdx.x;
  const int* counts = (L==0)?c0:(L==1)?c1:c2;
  int* indptr2      = (L==0)?ip0:(L==1)?ip1:ip2;
  int* cursor       = (L==0)?cu0:(L==1)?cu1:cu2;
  u16* ell_src      = (L==0)?sd0:(L==1)?sd1:sd2;
  int n             = (L==0)?n0:(L==1)?n1:n2;
  __shared__ int part[1024];
  int tid = threadIdx.x;
  int base = tid*4;
  int v0=0,v1=0,v2=0,v3=0;
  if (base+0<n) v0 = (counts[base+0]+4)&~3;
  if (base+1<n) v1 = (counts[base+1]+4)&~3;
  if (base+2<n) v2 = (counts[base+2]+4)&~3;
  if (base+3<n) v3 = (counts[base+3]+4)&~3;
  part[tid] = v0+v1+v2+v3;
  __syncthreads();
  for (int off=1; off<1024; off<<=1){
    int t2 = (tid>=off)?part[tid-off]:0;
    __syncthreads();
    part[tid] += t2;
    __syncthreads();
  }
  int run = (tid>0)?part[tid-1]:0;
  if (base+0<n){ indptr2[base+0]=run; cursor[base+0]=run+1; ell_src[run]=(u16)(base+0); run+=v0; }
  if (base+1<n){ indptr2[base+1]=run; cursor[base+1]=run+1; ell_src[run]=(u16)(base+1); run+=v1; }
  if (base+2<n){ indptr2[base+2]=run; cursor[base+2]=run+1; ell_src[run]=(u16)(base+2); run+=v2; }
  if (base+3<n){ indptr2[base+3]=run; cursor[base+3]=run+1; ell_src[run]=(u16)(base+3); run+=v3; }
  if (tid==0) indptr2[n] = part[1023];
}

__global__ __launch_bounds__(256) void scatter_all_k(const int* __restrict__ el0, const int* __restrict__ el1,
                         const int* __restrict__ el2, int* __restrict__ cu0, int* __restrict__ cu1,
                         int* __restrict__ cu2, u16* __restrict__ sd0, u16* __restrict__ sd1,
                         u16* __restrict__ sd2, int n0, int n1, int n2){
  int t = blockIdx.x*256 + threadIdx.x;
  int L = blockIdx.y;
  const int* el = (L==0)?el0:(L==1)?el1:el2;
  int* cursor   = (L==0)?cu0:(L==1)?cu1:cu2;
  u16* ell_src  = (L==0)?sd0:(L==1)?sd1:sd2;
  int n         = (L==0)?n0:(L==1)?n1:n2;
  if (t < n){
    int dd = el[n + t];
    int p = atomicAdd(&cursor[dd], 1);
    ell_src[p] = (u16)el[t];
  }
}

// counting sort of pool-pairs by max(deg) -> perm (shared by all graphs)
__global__ __launch_bounds__(1024) void pairsort_k(const int* __restrict__ c0, const int* __restrict__ c1,
                         const int* __restrict__ c2, u16* __restrict__ pm0, u16* __restrict__ pm1,
                         u16* __restrict__ pm2, int np0, int np1, int np2){
  int L = blockIdx.x;
  const int* counts = (L==0)?c0:(L==1)?c1:c2;
  u16* perm = (L==0)?pm0:(L==1)?pm1:pm2;
  int np    = (L==0)?np0:(L==1)?np1:np2;
  __shared__ int hist[64];
  __shared__ int pos[64];
  int t = threadIdx.x;
  if (t < 64) hist[t] = 0;
  __syncthreads();
  for (int p=t; p<np; p+=1024){
    int k = min(max(counts[2*p], counts[2*p+1]), 63);
    atomicAdd(&hist[k], 1);
  }
  __syncthreads();
  if (t == 0){ int run=0; for (int i=0;i<64;i++){ pos[i]=run; run+=hist[i]; } }
  __syncthreads();
  for (int p=t; p<np; p+=1024){
    int k = min(max(counts[2*p], counts[2*p+1]), 63);
    int q = atomicAdd(&pos[k], 1);
    perm[q] = (u16)p;
  }
}

// ---------------- layer-0 GEMM: x[n,3] @ W0[3,64] -> h bf16, LOG2E-prescaled al_s/al_d ----------------
__global__ __launch_bounds__(256) void gemm3_k(const float* __restrict__ x, const float* __restrict__ Wg,
                        const float* __restrict__ asrc, const float* __restrict__ adst,
                        u16* __restrict__ h, float* __restrict__ als, float* __restrict__ ald, int nrows8)
{
  const int l = threadIdx.x & 63;
  const int g = l >> 3;
  const int o = l & 7;
  float W0[8], W1[8], W2[8];
  float vs0=0.f,vs1=0.f,vs2=0.f,vd0=0.f,vd1=0.f,vd2=0.f;
  #pragma unroll
  for (int j=0;j<8;j++){
    W0[j] = Wg[      o*8 + j];
    W1[j] = Wg[ 64 + o*8 + j];
    W2[j] = Wg[128 + o*8 + j];
    float as = asrc[o*8 + j], ad = adst[o*8 + j];
    vs0 = fmaf(W0[j], as, vs0); vs1 = fmaf(W1[j], as, vs1); vs2 = fmaf(W2[j], as, vs2);
    vd0 = fmaf(W0[j], ad, vd0); vd1 = fmaf(W1[j], ad, vd1); vd2 = fmaf(W2[j], ad, vd2);
  }
  #pragma unroll
  for (int off=1; off<8; off<<=1){
    vs0 += __shfl_xor(vs0,off); vs1 += __shfl_xor(vs1,off); vs2 += __shfl_xor(vs2,off);
    vd0 += __shfl_xor(vd0,off); vd1 += __shfl_xor(vd1,off); vd2 += __shfl_xor(vd2,off);
  }
  int wv = blockIdx.x*4 + (int)(threadIdx.x>>6);
  int stride = gridDim.x*4;
  for (int blk = wv; blk < nrows8; blk += stride){
    int r = blk*8 + g;
    float x0 = x[(size_t)r*3+0];
    float x1 = x[(size_t)r*3+1];
    float x2 = x[(size_t)r*3+2];
    u32 pk[4];
    #pragma unroll
    for (int j=0;j<8;j+=2){
      float a0 = fmaf(x0, W0[j],   fmaf(x1, W1[j],   x2*W2[j]));
      float a1 = fmaf(x0, W0[j+1], fmaf(x1, W1[j+1], x2*W2[j+1]));
      pk[j>>1] = (u32)f2bf(a0) | ((u32)f2bf(a1) << 16);
    }
    ((int4*)(h + ((size_t)r << 6)))[o] = make_int4((int)pk[0],(int)pk[1],(int)pk[2],(int)pk[3]);
    if (o == 0){
      als[r] = LOG2E * fmaf(x2, vs2, fmaf(x1, vs1, x0*vs0));
      ald[r] = LOG2E * fmaf(x2, vd2, fmaf(x1, vd1, x0*vd0));
    }
  }
}

// ---------------- prep (layers 1/2): BN finish of prev layer + W' frags + als/ald B-tile ----------------
__global__ __launch_bounds__(128) void prep_w_k(const float* __restrict__ W, const float* __restrict__ asrc,
                        const float* __restrict__ adst, const float* __restrict__ scratch, float invN,
                        u16* __restrict__ wswz, float* __restrict__ cvec){
  __shared__ float mean_s[64], rstd_s[64], vs_s[64], vd_s[64], cv_s[64], acc[128];
  int t = threadIdx.x;
  float s = 0.f;
  #pragma unroll 8
  for (int b2=0;b2<256;b2++) s += scratch[b2*128 + t];
  acc[t] = s;
  __syncthreads();
  if (t < 64){
    float m = acc[t]*invN;
    float var = acc[64+t]*invN - m*m;
    mean_s[t] = m; rstd_s[t] = rsqrtf(var + BN_EPS);
  }
  __syncthreads();
  if (t < 64){
    float c = 0.f;
    for (int k=0;k<64;k++) c = fmaf(mean_s[k]*rstd_s[k], W[k*64+t], c);
    cv_s[t] = c; cvec[t] = c;
    float vs = 0.f, vd = 0.f;
    for (int col=0; col<64; col++){
      float wv = W[t*64+col];
      vs = fmaf(wv, asrc[col], vs);
      vd = fmaf(wv, adst[col], vd);
    }
    vs_s[t] = rstd_s[t]*vs; vd_s[t] = rstd_s[t]*vd;
  }
  __syncthreads();
  if (t == 0){
    float cs=0.f, cd=0.f;
    for (int col=0; col<64; col++){ cs = fmaf(cv_s[col], asrc[col], cs); cd = fmaf(cv_s[col], adst[col], cd); }
    cvec[64] = cs; cvec[65] = cd;
  }
  if (t < 64){
    #pragma unroll
    for (int f=0; f<8; f++){
      int tt = f >> 1, ch = f & 1;
      #pragma unroll
      for (int j=0; j<8; j++){
        int k   = ch*32 + (t>>4)*8 + j;
        int col = tt*16 + (t&15);
        wswz[(f*64 + t)*8 + j] = f2bf(rstd_s[k] * W[k*64 + col]);
      }
    }
    #pragma unroll
    for (int f=8; f<10; f++){
      int ch = f - 8;
      #pragma unroll
      for (int j=0; j<8; j++){
        int k = ch*32 + (t>>4)*8 + j;
        int colp = t & 15;
        float val = (colp==0)? vs_s[k] : (colp==1)? vd_s[k] : 0.f;
        wswz[(f*64 + t)*8 + j] = f2bf(val);
      }
    }
  }
}

// ---------------- layers 1/2 GEMM via MFMA: h = P @ W' - c; LOG2E-prescaled als/ald ----------------
__global__ __launch_bounds__(256) void gemm64_mfma_k(const u16* __restrict__ Pin, const u16* __restrict__ wswz,
                        const float* __restrict__ cvec,
                        u16* __restrict__ h, float* __restrict__ als, float* __restrict__ ald, int nblk16)
{
  const int l = threadIdx.x & 63;
  const int q = l >> 4;
  const int c = l & 15;
  short8 B[10];
  const int4* wsw = (const int4*)wswz;
  #pragma unroll
  for (int f=0; f<10; f++){
    int4 v = wsw[f*64 + l];
    B[f] = *(short8*)&v;
  }
  float cl[4];
  #pragma unroll
  for (int t=0;t<4;t++) cl[t] = cvec[t*16+c];
  const float const_s = cvec[64], const_d = cvec[65];
  int gw = blockIdx.x*4 + (int)(threadIdx.x>>6);
  int stride = gridDim.x*4;
  for (int blk = gw; blk < nblk16; blk += stride){
    size_t rowbase = (size_t)blk*16;
    const int4* arow = (const int4*)(Pin + (rowbase + c)*64);
    int4 a0v = arow[q];
    int4 a1v = arow[4+q];
    short8 A0 = *(short8*)&a0v, A1 = *(short8*)&a1v;
    f32x4 C0={0.f,0.f,0.f,0.f}, C1=C0, C2=C0, C3=C0, C4=C0;
    C0 = __builtin_amdgcn_mfma_f32_16x16x32_bf16(A0, B[0], C0, 0,0,0);
    C0 = __builtin_amdgcn_mfma_f32_16x16x32_bf16(A1, B[1], C0, 0,0,0);
    C1 = __builtin_amdgcn_mfma_f32_16x16x32_bf16(A0, B[2], C1, 0,0,0);
    C1 = __builtin_amdgcn_mfma_f32_16x16x32_bf16(A1, B[3], C1, 0,0,0);
    C2 = __builtin_amdgcn_mfma_f32_16x16x32_bf16(A0, B[4], C2, 0,0,0);
    C2 = __builtin_amdgcn_mfma_f32_16x16x32_bf16(A1, B[5], C2, 0,0,0);
    C3 = __builtin_amdgcn_mfma_f32_16x16x32_bf16(A0, B[6], C3, 0,0,0);
    C3 = __builtin_amdgcn_mfma_f32_16x16x32_bf16(A1, B[7], C3, 0,0,0);
    C4 = __builtin_amdgcn_mfma_f32_16x16x32_bf16(A0, B[8], C4, 0,0,0);
    C4 = __builtin_amdgcn_mfma_f32_16x16x32_bf16(A1, B[9], C4, 0,0,0);
    #pragma unroll
    for (int t=0;t<4;t++){
      f32x4 C = (t==0)?C0:(t==1)?C1:(t==2)?C2:C3;
      #pragma unroll
      for (int reg=0;reg<4;reg++){
        h[(rowbase + q*4 + reg)*64 + t*16 + c] = f2bf(C[reg] - cl[t]);
      }
    }
    if (c == 0){
      #pragma unroll
      for (int reg=0;reg<4;reg++) als[rowbase + q*4 + reg] = (C4[reg] - const_s) * LOG2E;
    } else if (c == 1){
      #pragma unroll
      for (int reg=0;reg<4;reg++) ald[rowbase + q*4 + reg] = (C4[reg] - const_d) * LOG2E;
    }
  }
}

// ---------------- GAT gather + inline edge-softmax + bias + relu + pairwise max-pool ----------------
// r4 structure (126.5us L0) + maskless pipeline + LOG2E prescale. r16's exp2f regressed
// (libm exp2f = guarded multi-inst sequence: VGPR 32->36, VALU-time +9us). Fix: raw
// v_exp_f32 via __builtin_amdgcn_exp2f -- per-edge weight chain = add + fmax*mul + exp.
__global__ __launch_bounds__(256) void gat_pool_k(const u16* __restrict__ h, const float* __restrict__ bias,
                      const int* __restrict__ indptr2, const int* __restrict__ counts,
                      const u16* __restrict__ perm, const u16* __restrict__ ell_src,
                      const float* __restrict__ als, const float* __restrict__ ald,
                      u16* __restrict__ P, int log2NS, int nwaves)
{
  const int l = threadIdx.x & 63;
  const int g = l >> 3;
  const int o = l & 7;
  const int NB  = gridDim.x;
  const int bid = blockIdx.x;
  const int lb  = (bid & 7) * (NB >> 3) + (bid >> 3);   // XCD swizzle
  const int wv  = lb * 4 + (int)(threadIdx.x >> 6);
  if (wv >= nwaves) return;
  const int wvu = __builtin_amdgcn_readfirstlane(wv);   // wave-uniform -> SGPR-based addressing

  const int wbits = log2NS - 3;
  const int b    = wvu >> wbits;
  const int widx = wvu & ((1 << wbits) - 1);
  const int pairslot = widx*4 + (g >> 1);
  const int prow = perm[pairslot];
  const int d = 2*prow + (g & 1);
  const int nmask = (1 << log2NS) - 1;
  const int base = b << log2NS;

  const char* __restrict__ hbase  = (const char*)(h + ((size_t)base << 6));   // uniform
  const char* __restrict__ albase = (const char*)(als + base);                // uniform
  const char* __restrict__ elb    = (const char*)ell_src;                     // uniform
  const u32 olane16 = (u32)o << 4;

  const int p0  = indptr2[d];
  const int cnt = counts[d] + 1;
  const float ald_d = ald[base + d];
  const u32 moff = (u32)p0 << 1;

  v2f a01={0.f,0.f}, a23={0.f,0.f}, a45={0.f,0.f}, a67={0.f,0.f};
  float z = 0.f;

  // prologue: h+als for items 0,1; prefetch meta for item 2
  u32 s0 = (u32)(*(const u16*)(elb + moff)) & nmask;
  int4 H0 = *(const int4*)(hbase + ((s0 << 7) + olane16));
  float al0 = *(const float*)(albase + (s0 << 2));
  u32 s1 = (u32)(*(const u16*)(elb + moff + 2)) & nmask;
  int4 H1 = *(const int4*)(hbase + ((s1 << 7) + olane16));
  float al1 = *(const float*)(albase + (s1 << 2));
  int m2 = *(const u16*)(elb + moff + 4);

  #pragma unroll 4
  for (int it = 0; it < cnt; ++it){
    // issue h+als for item it+2 (meta m2)
    u32 s2 = (u32)m2 & nmask;
    int4 Hn = *(const int4*)(hbase + ((s2 << 7) + olane16));
    float al2 = *(const float*)(albase + (s2 << 2));
    // meta for item it+3
    int m3 = *(const u16*)(elb + (moff + ((u32)(it + 3) << 1)));
    // consume item it: w = v_exp_f32(max(t, 0.2t))  [als/ald prescaled by LOG2E; no mask]
    float t = al0 + ald_d;
    float w = __builtin_amdgcn_exp2f(fmaxf(t, NEG_SLOPE*t));
    z += w;
    v2f w2 = {w, w};
    a01 += (v2f){ __uint_as_float(((u32)H0.x) << 16), __uint_as_float(((u32)H0.x) & 0xffff0000u) } * w2;
    a23 += (v2f){ __uint_as_float(((u32)H0.y) << 16), __uint_as_float(((u32)H0.y) & 0xffff0000u) } * w2;
    a45 += (v2f){ __uint_as_float(((u32)H0.z) << 16), __uint_as_float(((u32)H0.z) & 0xffff0000u) } * w2;
    a67 += (v2f){ __uint_as_float(((u32)H0.w) << 16), __uint_as_float(((u32)H0.w) & 0xffff0000u) } * w2;
    // shift pipeline (erased by unroll + copy-prop)
    m2 = m3;
    H0 = H1; al0 = al1;
    H1 = Hn; al1 = al2;
  }

  float rz = __builtin_amdgcn_rcpf(z);
  const float* bp = bias + (o << 3);          // loaded after the loop: not live across it
  float4 bA = *(const float4*)(bp);
  float4 bB = *(const float4*)(bp + 4);
  float q0 = fmaxf(fmaf(a01.x, rz, bA.x), 0.f);
  float q1 = fmaxf(fmaf(a01.y, rz, bA.y), 0.f);
  float q2 = fmaxf(fmaf(a23.x, rz, bA.z), 0.f);
  float q3 = fmaxf(fmaf(a23.y, rz, bA.w), 0.f);
  float q4 = fmaxf(fmaf(a45.x, rz, bB.x), 0.f);
  float q5 = fmaxf(fmaf(a45.y, rz, bB.y), 0.f);
  float q6 = fmaxf(fmaf(a67.x, rz, bB.z), 0.f);
  float q7 = fmaxf(fmaf(a67.y, rz, bB.w), 0.f);
  q0 = fmaxf(q0, __shfl_xor(q0, 8));
  q1 = fmaxf(q1, __shfl_xor(q1, 8));
  q2 = fmaxf(q2, __shfl_xor(q2, 8));
  q3 = fmaxf(q3, __shfl_xor(q3, 8));
  q4 = fmaxf(q4, __shfl_xor(q4, 8));
  q5 = fmaxf(q5, __shfl_xor(q5, 8));
  q6 = fmaxf(q6, __shfl_xor(q6, 8));
  q7 = fmaxf(q7, __shfl_xor(q7, 8));
  if ((g & 1) == 0){
    u32 w0 = (u32)f2bf(q0) | ((u32)f2bf(q1) << 16);
    u32 w1 = (u32)f2bf(q2) | ((u32)f2bf(q3) << 16);
    u32 w2p = (u32)f2bf(q4) | ((u32)f2bf(q5) << 16);
    u32 w3 = (u32)f2bf(q6) | ((u32)f2bf(q7) << 16);
    char* Pb = (char*)P + (((size_t)b << (log2NS - 1)) << 7);   // uniform base
    *(int4*)(Pb + (((u32)prow << 7) + olane16)) = make_int4((int)w0,(int)w1,(int)w2p,(int)w3);
  }
}

// ---------------- BatchNorm stats (stage 1) ----------------
__global__ __launch_bounds__(256) void bn_stats_k(const u16* __restrict__ P, float* __restrict__ scratch, int iters){
  const int l = threadIdx.x & 63;
  int gw = blockIdx.x*4 + (threadIdx.x>>6);
  int GW = gridDim.x*4;
  float s = 0.f, s2 = 0.f;
  #pragma unroll 4
  for (int i = 0; i < iters; i++){
    int r = gw + i*GW;
    float v = bf2f(P[(size_t)r*64 + l]);
    s += v; s2 = fmaf(v, v, s2);
  }
  __shared__ float ls[256], ls2[256];
  ls[threadIdx.x] = s; ls2[threadIdx.x] = s2;
  __syncthreads();
  if (threadIdx.x < 64){
    float S  = ls[threadIdx.x] + ls[threadIdx.x+64] + ls[threadIdx.x+128] + ls[threadIdx.x+192];
    float S2 = ls2[threadIdx.x] + ls2[threadIdx.x+64] + ls2[threadIdx.x+128] + ls2[threadIdx.x+192];
    scratch[blockIdx.x*128 + threadIdx.x] = S;
    scratch[blockIdx.x*128 + 64 + threadIdx.x] = S2;
  }
}

__global__ __launch_bounds__(128) void bn_finish_k(const float* __restrict__ scratch, float* __restrict__ stats,
                                                   int nblocks, float invN){
  __shared__ float accs[128];
  int j = threadIdx.x;
  float s = 0.f;
  #pragma unroll 8
  for (int b=0;b<nblocks;b++) s += scratch[b*128 + j];
  accs[j] = s;
  __syncthreads();
  if (j < 64){
    float m = accs[j]*invN;
    float var = accs[j+64]*invN - m*m;
    stats[j] = m;
    stats[64+j] = rsqrtf(var + BN_EPS);
  }
}

// ---------------- final BN apply: bf16 P -> f32 out ----------------
__global__ __launch_bounds__(256) void bn_apply_k(const u32* __restrict__ P2, const float* __restrict__ stats,
                                                  float4* __restrict__ out, int nq){
  int t = blockIdx.x*256 + threadIdx.x;
  if (t >= nq) return;
  int l = (t*4) & 63;
  u32 v0 = P2[t*2], v1 = P2[t*2+1];
  float4 r;
  r.x = (__uint_as_float((v0 & 0xffffu) << 16) - stats[l+0]) * stats[64+l+0];
  r.y = (__uint_as_float( v0 & 0xffff0000u    ) - stats[l+1]) * stats[64+l+1];
  r.z = (__uint_as_float((v1 & 0xffffu) << 16) - stats[l+2]) * stats[64+l+2];
  r.w = (__uint_as_float( v1 & 0xffff0000u    ) - stats[l+3]) * stats[64+l+3];
  out[t] = r;
}

// ---------------- launcher ----------------
extern "C" void kernel_launch(void* const* d_in, const int* in_sizes, int n_in,
                              void* d_out, int out_size, void* d_ws, size_t ws_size,
                              hipStream_t stream)
{
  const float* x      = (const float*)d_in[0];
  const float* Wl[3]  = {(const float*)d_in[1], (const float*)d_in[7],  (const float*)d_in[13]};
  const float* asl[3] = {(const float*)d_in[2], (const float*)d_in[8],  (const float*)d_in[14]};
  const float* adl[3] = {(const float*)d_in[3], (const float*)d_in[9],  (const float*)d_in[15]};
  const float* bl[3]  = {(const float*)d_in[4], (const float*)d_in[10], (const float*)d_in[16]};
  const int*   el[3]  = {(const int*)d_in[5],   (const int*)d_in[11],   (const int*)d_in[17]};

  const int NS[4]  = {4096, 2048, 1024, 512};
  const int EPB[3] = {32768, 16384, 8192};
  const int LOG2NS[3] = {12, 11, 10};
  const int ECAP[3] = {32768+4*4096, 16384+4*2048, 8192+4*1024};  // 49152, 24576, 12288
  const int BATCH = 256;

  char* ws = (char*)d_ws;
  size_t off = 0;
  auto alloc = [&](size_t bytes)->char*{
    char* p = ws + off; off += (bytes + 255) & ~(size_t)255; return p;
  };

  u16*   hbuf    = (u16*)alloc((size_t)BATCH*NS[0]*64*2);            // 128 MB
  u16*   Pbuf    = (u16*)alloc((size_t)BATCH*NS[1]*64*2);            //  64 MB
  float* als     = (float*)alloc((size_t)BATCH*NS[0]*4);             //   4 MB
  float* ald     = (float*)alloc((size_t)BATCH*NS[0]*4);             //   4 MB
  float* scratch = (float*)alloc(256*128*4);
  float* stats   = (float*)alloc(128*4);
  u16*   wswz    = (u16*)alloc(10*64*8*2);
  float* cvec    = (float*)alloc(128*4);
  int* counts_all = (int*)alloc((size_t)(NS[0]+NS[1]+NS[2])*4);
  int* cursor_all = (int*)alloc((size_t)(NS[0]+NS[1]+NS[2])*4);
  int *counts[3], *cursor[3], *indptr2[3];
  u16* ell_src[3];
  u16* perm[3];
  counts[0]=counts_all; counts[1]=counts_all+NS[0]; counts[2]=counts_all+NS[0]+NS[1];
  cursor[0]=cursor_all; cursor[1]=cursor_all+NS[0]; cursor[2]=cursor_all+NS[0]+NS[1];
  for (int i=0;i<3;i++){
    indptr2[i] = (int*)alloc((size_t)(NS[i]+1)*4);
    ell_src[i] = (u16*)alloc((size_t)(ECAP[i]+16)*2);
    perm[i]    = (u16*)alloc((size_t)NS[i]);      // NS/2 pairs * 2B
  }
  if (off > ws_size) return;

  // ---- build ----
  int ctot = NS[0]+NS[1]+NS[2];
  {
    dim3 ginit((ECAP[0]+16+255)/256, 4);
    init_k<<<ginit, 256, 0, stream>>>(counts_all, ell_src[0], ell_src[1], ell_src[2],
                                      ctot, ECAP[0]+16, ECAP[1]+16, ECAP[2]+16);
    dim3 ghist(EPB[0]/256, 3);
    hist_all_k<<<ghist, 256, 0, stream>>>(el[0], el[1], el[2], counts[0], counts[1], counts[2],
                                          EPB[0], EPB[1], EPB[2]);
    scan_all_k<<<3, 1024, 0, stream>>>(counts[0], counts[1], counts[2],
                                       indptr2[0], indptr2[1], indptr2[2],
                                       cursor[0], cursor[1], cursor[2],
                                       ell_src[0], ell_src[1], ell_src[2],
                                       NS[0], NS[1], NS[2]);
    scatter_all_k<<<ghist, 256, 0, stream>>>(el[0], el[1], el[2],
                                             cursor[0], cursor[1], cursor[2],
                                             ell_src[0], ell_src[1], ell_src[2],
                                             EPB[0], EPB[1], EPB[2]);
    pairsort_k<<<3, 1024, 0, stream>>>(counts[0], counts[1], counts[2],
                                       perm[0], perm[1], perm[2],
                                       NS[0]/2, NS[1]/2, NS[2]/2);
  }

  // ---- layers ----
  for (int i=0;i<3;i++){
    int ntot = BATCH*NS[i];

    if (i==0){
      gemm3_k<<<1024, 256, 0, stream>>>(x, Wl[0], asl[0], adl[0], hbuf, als, ald, ntot/8);
    } else {
      float invN = 1.0f / (float)(BATCH*NS[i]);   // prev pooled rows = BATCH*NS[i-1]/2 = BATCH*NS[i]
      prep_w_k<<<1, 128, 0, stream>>>(Wl[i], asl[i], adl[i], scratch, invN, wswz, cvec);
      gemm64_mfma_k<<<2048, 256, 0, stream>>>(Pbuf, wswz, cvec, hbuf, als, ald, ntot/16);
    }

    int nwaves = ntot/8;
    gat_pool_k<<<nwaves/4, 256, 0, stream>>>(hbuf, bl[i], indptr2[i], counts[i], perm[i],
                                             ell_src[i], als, ald,
                                             Pbuf, LOG2NS[i], nwaves);

    bn_stats_k<<<256, 256, 0, stream>>>(Pbuf, scratch, (ntot/2)/1024);
  }

  // final BN: finish stats of layer 2, then materialize into d_out
  bn_finish_k<<<1, 128, 0, stream>>>(scratch, stats, 256, 1.0f/(float)(BATCH*NS[3]));
  int nq = out_size/4;
  bn_apply_k<<<(nq+255)/256, 256, 0, stream>>>((const u32*)Pbuf, stats, (float4*)d_out, nq);
}